// Round 9
// baseline (320.955 us; speedup 1.0000x reference)
//
#include <hip/hip_runtime.h>
#include <stdint.h>
#include <math.h>

#define S_LEN 2048
#define NH 16

typedef __attribute__((ext_vector_type(8))) short bf16x8;
typedef __attribute__((ext_vector_type(4))) float f32x4;
typedef __attribute__((ext_vector_type(16))) float f32x16;
typedef unsigned short ush;

__device__ __forceinline__ ush f2bf(float f) {   // RNE float->bf16
  union { float f; unsigned u; } v; v.f = f;
  unsigned x = v.u;
  return (ush)((x + 0x7fffu + ((x >> 16) & 1u)) >> 16);
}
__device__ __forceinline__ float bf2f(ush b) {
  union { unsigned u; float f; } v; v.u = ((unsigned)b) << 16;
  return v.f;
}
__device__ __forceinline__ ush f2h(float f) {    // RNE float->fp16
  _Float16 h = (_Float16)f;
  union { _Float16 h; ush u; } v; v.h = h;
  return v.u;
}
__device__ __forceinline__ float h2f(ush u) {
  union { ush u; _Float16 h; } v; v.u = u;
  return (float)v.h;
}

// async global->LDS, 16B/lane; LDS dest = wave-uniform base + lane*16
__device__ __forceinline__ void gload_lds16(const ush* g, ush* l) {
  __builtin_amdgcn_global_load_lds((const __attribute__((address_space(1))) void*)g,
                                   (__attribute__((address_space(3))) void*)l, 16, 0, 0);
}

// ---------------- mega pack: all weights + x (fp16) + rope table, ONE launch ----------------
__global__ void mega_pack(const float* __restrict__ wq_down, const float* __restrict__ wkv_down,
                          const float* __restrict__ wk_rope, const float* __restrict__ wq_up,
                          const float* __restrict__ wq_rope, const float* __restrict__ wkv_up,
                          const float* __restrict__ wo, const float* __restrict__ x,
                          ush* __restrict__ wdh, ush* __restrict__ wqh, ush* __restrict__ wkvuh,
                          ush* __restrict__ woh, ush* __restrict__ xh, float* __restrict__ tab) {
  int idx = blockIdx.x * 256 + threadIdx.x;
  if (idx < 2359296) {  // fused down weights [wq_down|wkv_down|wk_rope|0] 1152x2048
    int r = idx >> 11, c = idx & 2047;
    float v = (r < 512) ? wq_down[(size_t)r * 2048 + c]
            : (r < 1024) ? wkv_down[(size_t)(r - 512) * 2048 + c]
            : (r < 1088) ? wk_rope[(size_t)(r - 1024) * 2048 + c] : 0.f;
    wdh[idx] = f2h(v);
    return;
  }
  idx -= 2359296;
  if (idx < 1572864) {  // fused [wq_up|wq_rope] 3072x512
    int r = idx >> 9, c = idx & 511;
    float v = (r < 2048) ? wq_up[(size_t)r * 512 + c] : wq_rope[(size_t)(r - 2048) * 512 + c];
    wqh[idx] = f2h(v);
    return;
  }
  idx -= 1572864;
  if (idx < 2097152) { wkvuh[idx] = f2h(wkv_up[idx]); return; }   // 4096x512
  idx -= 2097152;
  if (idx < 4194304) { woh[idx] = f2h(wo[idx]); return; }         // 2048x2048
  idx -= 4194304;
  if (idx < 4194304) { xh[idx] = f2h(x[idx]); return; }           // 2048x2048
  idx -= 4194304;
  if (idx < 65536) {  // rope table
    int tt = idx >> 5, i = idx & 31;
    float inv_freq = 1.0f / powf(10000.0f, (float)i * (1.0f / 32.0f));
    float fr = (float)tt * inv_freq;
    tab[idx] = sinf(fr);
    tab[65536 + idx] = cosf(fr);
  }
}

// ---------------- down GEMM BM=64,BN=64, single-barrier dbuf, fused epilogue ----------------
__global__ __launch_bounds__(256) void gemm_down(
    const ush* __restrict__ A, const ush* __restrict__ B,
    ush* __restrict__ cqh, ush* __restrict__ ckvh, float* __restrict__ krl) {
  constexpr int K = 2048;
  __shared__ __align__(16) ush As[2 * 64 * 32];
  __shared__ __align__(16) ush Bs[2 * 64 * 32];
  const int t = threadIdx.x, l = t & 63, w = t >> 6;
  const int wm = w & 1, wn = w >> 1;
  const int m0 = blockIdx.y * 64, n0 = blockIdx.x * 64;
  const int lm = l & 15, lq = l >> 4;
  const int lr = l >> 2, lc = (l & 3) * 8;

  f32x4 acc[2][2];
  const f32x4 zero = {0.f, 0.f, 0.f, 0.f};
#pragma unroll
  for (int i = 0; i < 2; i++)
#pragma unroll
    for (int j = 0; j < 2; j++) acc[i][j] = zero;

  const ush* Ag = A + (size_t)(m0 + w * 16 + lr) * K + lc;
  const ush* Bg = B + (size_t)(n0 + w * 16 + lr) * K + lc;

  // prologue stage k=0 -> buf0
  gload_lds16(Ag, As + w * 512);
  gload_lds16(Bg, Bs + w * 512);

  int cur = 0;
  for (int k0 = 0; k0 < K; k0 += 32) {
    asm volatile("s_waitcnt vmcnt(0)" ::: "memory");
    __builtin_amdgcn_s_barrier();
    __builtin_amdgcn_sched_barrier(0);
    if (k0 + 32 < K) {
      int nb = cur ^ 1;
      gload_lds16(Ag + k0 + 32, As + nb * 2048 + w * 512);
      gload_lds16(Bg + k0 + 32, Bs + nb * 2048 + w * 512);
    }
    __builtin_amdgcn_sched_barrier(0);
    const ush* Asc = As + cur * 2048;
    const ush* Bsc = Bs + cur * 2048;
    bf16x8 af[2], bfr[2];
#pragma unroll
    for (int i = 0; i < 2; i++)
      af[i] = *(const bf16x8*)(Asc + (wm * 32 + i * 16 + lm) * 32 + lq * 8);
#pragma unroll
    for (int j = 0; j < 2; j++)
      bfr[j] = *(const bf16x8*)(Bsc + (wn * 32 + j * 16 + lm) * 32 + lq * 8);
#pragma unroll
    for (int i = 0; i < 2; i++)
#pragma unroll
      for (int j = 0; j < 2; j++)
        acc[i][j] = __builtin_amdgcn_mfma_f32_16x16x32_f16(af[i], bfr[j], acc[i][j], 0, 0, 0);
    cur ^= 1;
  }

#pragma unroll
  for (int i = 0; i < 2; i++)
#pragma unroll
    for (int j = 0; j < 2; j++)
#pragma unroll
      for (int r = 0; r < 4; r++) {
        int mm = m0 + wm * 32 + i * 16 + lq * 4 + r;
        int nn = n0 + wn * 32 + j * 16 + lm;
        float v = acc[i][j][r];
        if (nn < 512)       cqh[(size_t)mm * 512 + nn] = f2h(v);
        else if (nn < 1024) ckvh[(size_t)mm * 512 + nn - 512] = f2h(v);
        else if (nn < 1088) krl[(size_t)mm * 64 + nn - 1024] = v;
      }
}

// ---------------- merged up GEMM (qup blocks [0,48), kvup [48,112)): BM=128,BN=64,K=512,
// single-barrier dbuf, fp16 out ----------------
__global__ __launch_bounds__(256) void gemm_up(
    const ush* __restrict__ cqh, const ush* __restrict__ wqh,
    const ush* __restrict__ ckvh, const ush* __restrict__ wkvuh,
    ush* __restrict__ qupf, ush* __restrict__ kvf) {
  constexpr int BM = 128, BN = 64, K = 512, FI = 4, FJ = 2;
  __shared__ __align__(16) ush As[2 * BM * 32];
  __shared__ __align__(16) ush Bs[2 * BN * 32];
  int bx = blockIdx.x;
  const ush* A; const ush* B; ush* C; int ldc;
  if (bx < 48) { A = cqh; B = wqh; C = qupf; ldc = 3072; }
  else { bx -= 48; A = ckvh; B = wkvuh; C = kvf; ldc = 4096; }
  const int t = threadIdx.x, l = t & 63, w = t >> 6;
  const int wm = w & 1, wn = w >> 1;
  const int m0 = blockIdx.y * BM, n0 = bx * BN;
  const int lm = l & 15, lq = l >> 4;
  const int lr = l >> 2, lc = (l & 3) * 8;

  f32x4 acc[FI][FJ];
  const f32x4 zero = {0.f, 0.f, 0.f, 0.f};
#pragma unroll
  for (int i = 0; i < FI; i++)
#pragma unroll
    for (int j = 0; j < FJ; j++) acc[i][j] = zero;

  const ush* Ag[2];
#pragma unroll
  for (int i = 0; i < 2; i++) Ag[i] = A + (size_t)(m0 + w * 32 + i * 16 + lr) * K + lc;
  const ush* Bg = B + (size_t)(n0 + w * 16 + lr) * K + lc;

#pragma unroll
  for (int i = 0; i < 2; i++) gload_lds16(Ag[i], As + w * 1024 + i * 512);
  gload_lds16(Bg, Bs + w * 512);

  int cur = 0;
  for (int k0 = 0; k0 < K; k0 += 32) {
    asm volatile("s_waitcnt vmcnt(0)" ::: "memory");
    __builtin_amdgcn_s_barrier();
    __builtin_amdgcn_sched_barrier(0);
    if (k0 + 32 < K) {
      int nb = cur ^ 1;
#pragma unroll
      for (int i = 0; i < 2; i++)
        gload_lds16(Ag[i] + k0 + 32, As + nb * 4096 + w * 1024 + i * 512);
      gload_lds16(Bg + k0 + 32, Bs + nb * 2048 + w * 512);
    }
    __builtin_amdgcn_sched_barrier(0);
    const ush* Asc = As + cur * 4096;
    const ush* Bsc = Bs + cur * 2048;
    bf16x8 af[FI], bfr[FJ];
#pragma unroll
    for (int i = 0; i < FI; i++)
      af[i] = *(const bf16x8*)(Asc + (wm * 64 + i * 16 + lm) * 32 + lq * 8);
#pragma unroll
    for (int j = 0; j < FJ; j++)
      bfr[j] = *(const bf16x8*)(Bsc + (wn * 32 + j * 16 + lm) * 32 + lq * 8);
#pragma unroll
    for (int i = 0; i < FI; i++)
#pragma unroll
      for (int j = 0; j < FJ; j++)
        acc[i][j] = __builtin_amdgcn_mfma_f32_16x16x32_f16(af[i], bfr[j], acc[i][j], 0, 0, 0);
    cur ^= 1;
  }

#pragma unroll
  for (int i = 0; i < FI; i++)
#pragma unroll
    for (int j = 0; j < FJ; j++)
#pragma unroll
      for (int r = 0; r < 4; r++) {
        int mm = m0 + wm * 64 + i * 16 + lq * 4 + r;
        int nn = n0 + wn * 32 + j * 16 + lm;
        C[(size_t)mm * ldc + nn] = f2h(acc[i][j][r]);
      }
}

// ---------------- out GEMM: BM=128,BN=64, single-barrier dbuf, f32 out ----------------
__global__ __launch_bounds__(256) void gemm_out(
    const ush* __restrict__ A, const ush* __restrict__ B, float* __restrict__ C,
    int K, int ldc) {
  constexpr int BM = 128, BN = 64, FI = 4, FJ = 2;
  __shared__ __align__(16) ush As[2 * BM * 32];
  __shared__ __align__(16) ush Bs[2 * BN * 32];
  const int t = threadIdx.x, l = t & 63, w = t >> 6;
  const int wm = w & 1, wn = w >> 1;
  const int m0 = blockIdx.y * BM, n0 = blockIdx.x * BN;
  const int lm = l & 15, lq = l >> 4;
  const int lr = l >> 2, lc = (l & 3) * 8;

  f32x4 acc[FI][FJ];
  const f32x4 zero = {0.f, 0.f, 0.f, 0.f};
#pragma unroll
  for (int i = 0; i < FI; i++)
#pragma unroll
    for (int j = 0; j < FJ; j++) acc[i][j] = zero;

  const ush* Ag[2];
#pragma unroll
  for (int i = 0; i < 2; i++) Ag[i] = A + (size_t)(m0 + w * 32 + i * 16 + lr) * K + lc;
  const ush* Bg = B + (size_t)(n0 + w * 16 + lr) * K + lc;

#pragma unroll
  for (int i = 0; i < 2; i++) gload_lds16(Ag[i], As + w * 1024 + i * 512);
  gload_lds16(Bg, Bs + w * 512);

  int cur = 0;
  for (int k0 = 0; k0 < K; k0 += 32) {
    asm volatile("s_waitcnt vmcnt(0)" ::: "memory");
    __builtin_amdgcn_s_barrier();
    __builtin_amdgcn_sched_barrier(0);
    if (k0 + 32 < K) {
      int nb = cur ^ 1;
#pragma unroll
      for (int i = 0; i < 2; i++)
        gload_lds16(Ag[i] + k0 + 32, As + nb * 4096 + w * 1024 + i * 512);
      gload_lds16(Bg + k0 + 32, Bs + nb * 2048 + w * 512);
    }
    __builtin_amdgcn_sched_barrier(0);
    const ush* Asc = As + cur * 4096;
    const ush* Bsc = Bs + cur * 2048;
    bf16x8 af[FI], bfr[FJ];
#pragma unroll
    for (int i = 0; i < FI; i++)
      af[i] = *(const bf16x8*)(Asc + (wm * 64 + i * 16 + lm) * 32 + lq * 8);
#pragma unroll
    for (int j = 0; j < FJ; j++)
      bfr[j] = *(const bf16x8*)(Bsc + (wn * 32 + j * 16 + lm) * 32 + lq * 8);
#pragma unroll
    for (int i = 0; i < FI; i++)
#pragma unroll
      for (int j = 0; j < FJ; j++)
        acc[i][j] = __builtin_amdgcn_mfma_f32_16x16x32_f16(af[i], bfr[j], acc[i][j], 0, 0, 0);
    cur ^= 1;
  }

#pragma unroll
  for (int i = 0; i < FI; i++)
#pragma unroll
    for (int j = 0; j < FJ; j++)
#pragma unroll
      for (int r = 0; r < 4; r++) {
        int mm = m0 + wm * 64 + i * 16 + lq * 4 + r;
        int nn = n0 + wn * 32 + j * 16 + lm;
        C[(size_t)mm * ldc + nn] = acc[i][j][r];
      }
}

// ---------------- builders: qb(scale-folded) + padded-tiled kbt + vtrans (merged) ----------------
__global__ void build_all(const ush* __restrict__ qupf, const ush* __restrict__ kvf,
                          const float* __restrict__ krl, const float* __restrict__ tab,
                          ush* __restrict__ qb, ush* __restrict__ kbt, ush* __restrict__ vtt) {
  const float scale = 0.07216878364870323f;  // 1/sqrt(192), folded into q
  if (blockIdx.x >= 50176) {  // vtrans: (s,d) fp16 -> (h,T,d[128],c[72]) bf16
    __shared__ ush Vt[128 * 72];
    int b = blockIdx.x - 50176;
    const int T = b & 31, h = b >> 5, t = threadIdx.x;
    const int key = t >> 5, d0 = (t & 31) * 4;
#pragma unroll
    for (int pass = 0; pass < 8; ++pass) {
      int k = key + pass * 8;
      int s = T * 64 + k;
      ushort4 v = *(const ushort4*)(kvf + (size_t)s * 4096 + 2048 + h * 128 + d0);
      Vt[(d0 + 0) * 72 + k] = f2bf(h2f(v.x));
      Vt[(d0 + 1) * 72 + k] = f2bf(h2f(v.y));
      Vt[(d0 + 2) * 72 + k] = f2bf(h2f(v.z));
      Vt[(d0 + 3) * 72 + k] = f2bf(h2f(v.w));
    }
    __syncthreads();
    ush* dst = vtt + (size_t)(h * 32 + T) * 9216;
    for (int off = t; off < 1152; off += 256) {
      int row = off / 9, c8 = (off % 9) * 8;
      *(bf16x8*)(dst + row * 72 + c8) = *(const bf16x8*)(Vt + row * 72 + c8);
    }
    return;
  }
  int idx = blockIdx.x * 256 + threadIdx.x;
  if (idx < 6291456) {  // qb (h,s,192), pre-scaled
    int d = idx % 192; int sh = idx / 192; int h = sh & 15; int s = sh >> 4;
    ush v;
    if (d < 128) {
      v = f2bf(h2f(qupf[(size_t)s * 3072 + h * 128 + d]) * scale);
    } else {
      int r = d - 128, i = r & 31;
      float sn = tab[s * 32 + i], cs = tab[65536 + s * 32 + i];
      const ush* qr = qupf + (size_t)s * 3072 + 2048 + h * 64;
      float xv = h2f(qr[r]);
      float other = (r < 32) ? -h2f(qr[r + 32]) : h2f(qr[r - 32]);
      v = f2bf((xv * cs + other * sn) * scale);
    }
    qb[((size_t)h * S_LEN + s) * 192 + d] = v;
    return;
  }
  idx -= 6291456;
  if (idx < 6553600) {  // kbt (h,T,key[64],c[200])
    int c = idx % 200; int r2 = idx / 200;
    int key = r2 & 63; int r3 = r2 >> 6; int T = r3 & 31; int h = r3 >> 5;
    int s = T * 64 + key;
    ush v = 0;
    if (c < 128) {
      v = f2bf(h2f(kvf[(size_t)s * 4096 + h * 128 + c]));
    } else if (c < 192) {
      int r = c - 128, i = r & 31;
      float sn = tab[s * 32 + i], cs = tab[65536 + s * 32 + i];
      const float* kr = krl + (size_t)s * 64;
      float xv = kr[r];
      float other = (r < 32) ? -kr[r + 32] : kr[r - 32];
      v = f2bf(xv * cs + other * sn);
    }
    kbt[((size_t)(h * 32 + T) * 64 + key) * 200 + c] = v;
  }
}

// ---------------- flash attention v8: 4-wave blocks, z=3 -> 768 blocks = 3 blocks/CU
// (3 waves/SIMD; combined regs ~148 <= 170), K dbuf LDS 51.2 KB, V from global ----------------
__global__ __launch_bounds__(256, 3) void attn_fused(
    const ush* __restrict__ qb, const ush* __restrict__ kbt, const ush* __restrict__ vtt,
    ush* __restrict__ opart, float* __restrict__ ml) {
  __shared__ __align__(16) ush Ks[2][64 * 200];   // 2 x 25.6 KB = 51.2 KB; 3 blocks/CU fit
  const int t = threadIdx.x, l = t & 63, w = t >> 6;   // 4 waves
  // XCD swizzle: 768 blocks, 96 per XCD, qx-major so blocks sharing (h,z) K/V are co-XCD
  const int id = blockIdx.x + 16 * (blockIdx.y + 16 * blockIdx.z);
  const int wid = (id & 7) * 96 + (id >> 3);
  const int qx = wid & 15, h = (wid >> 4) & 15, z = wid >> 8;   // z in [0,3)
  const int qrow0 = qx * 128 + w * 32;
  const int ln = l & 31, lh = l >> 5;
  const int t0 = z * 11, nt = (z == 2) ? 10 : 11;   // KV tiles 11/11/10

  bf16x8 qf[12];
#pragma unroll
  for (int st = 0; st < 12; st++)
    qf[st] = *(const bf16x8*)(qb + ((size_t)h * S_LEN + qrow0 + ln) * 192 + st * 16 + lh * 8);
#pragma unroll
  for (int st = 0; st < 12; st++) asm volatile("" : "+v"(qf[st]));

  f32x16 o[4];
#pragma unroll
  for (int i = 0; i < 4; i++)
#pragma unroll
    for (int r = 0; r < 16; r++) o[i][r] = 0.f;
  float ps = 0.f;  // per-lane sum of exp; partner lane (l^32) holds other half

  const ush* kbase = kbt + (size_t)(h * 32 + t0) * 12800;
  const ush* vbase = vtt + (size_t)(h * 32 + t0) * 9216;
  const ush* vrow = vbase + ln * 72 + lh * 8;   // per-lane V base (d-row ln, key-group lh)

  // softmax pack: sv (16 scores) -> exp -> bf16 pairs -> lane^32 half-exchange
  auto smpack = [&ps](const f32x16& svv, bf16x8& f0, bf16x8& f1) {
    unsigned pk8[8];
#pragma unroll
    for (int g = 0; g < 4; g++) {
      float p0 = __expf(svv[4 * g + 0]);   // scale pre-folded into q
      float p1 = __expf(svv[4 * g + 1]);
      float p2 = __expf(svv[4 * g + 2]);
      float p3 = __expf(svv[4 * g + 3]);
      ps += (p0 + p1) + (p2 + p3);
      unsigned lo, hi;
      asm("v_cvt_pk_bf16_f32 %0, %1, %2" : "=v"(lo) : "v"(p0), "v"(p1));
      asm("v_cvt_pk_bf16_f32 %0, %1, %2" : "=v"(hi) : "v"(p2), "v"(p3));
      pk8[2 * g] = lo; pk8[2 * g + 1] = hi;
    }
    asm("v_permlane32_swap_b32 %0, %1" : "+v"(pk8[0]), "+v"(pk8[2]));
    asm("v_permlane32_swap_b32 %0, %1" : "+v"(pk8[1]), "+v"(pk8[3]));
    asm("v_permlane32_swap_b32 %0, %1" : "+v"(pk8[4]), "+v"(pk8[6]));
    asm("v_permlane32_swap_b32 %0, %1" : "+v"(pk8[5]), "+v"(pk8[7]));
    union { unsigned d[4]; bf16x8 v; } u0, u1;
    u0.d[0] = pk8[0]; u0.d[1] = pk8[1]; u0.d[2] = pk8[2]; u0.d[3] = pk8[3];
    u1.d[0] = pk8[4]; u1.d[1] = pk8[5]; u1.d[2] = pk8[6]; u1.d[3] = pk8[7];
    f0 = u0.v; f1 = u1.v;
  };

  // prologue: stage K[0] -> buf 0 (25 chunks of 1 KB over 4 waves)
  for (int c = w; c < 25; c += 4) gload_lds16(kbase + c * 512 + l * 8, &Ks[0][c * 512]);

  int cur = 0;
  for (int it = 0; it < nt; ++it) {
    // drain K staging for tile it (issued a full iteration ago), publish buffer
    asm volatile("s_waitcnt vmcnt(0)" ::: "memory");
    __builtin_amdgcn_s_barrier();
    __builtin_amdgcn_sched_barrier(0);
    // prefetch K[it+1] into the buffer QK(it-1) just vacated; full iteration in flight
    if (it + 1 < nt) {
      const ush* ksrc = kbase + (size_t)(it + 1) * 12800;
      ush* kd = &Ks[cur ^ 1][0];
      for (int c = w; c < 25; c += 4) gload_lds16(ksrc + c * 512 + l * 8, kd + c * 512);
    }
    __builtin_amdgcn_sched_barrier(0);

    const ush* Kb = &Ks[cur][0];
    const ush* vt = vrow + (size_t)it * 9216;   // V tile for this iteration (global, L2-hot)

    // ---- kb0: QK0 -> SM0 -> PV0 ----
    {
      f32x16 sv0;
#pragma unroll
      for (int r = 0; r < 16; r++) sv0[r] = 0.f;
      __builtin_amdgcn_s_setprio(1);
#pragma unroll
      for (int st = 0; st < 12; st++) {
        bf16x8 af = *(const bf16x8*)(Kb + ln * 200 + st * 16 + lh * 8);
        sv0 = __builtin_amdgcn_mfma_f32_32x32x16_bf16(af, qf[st], sv0, 0, 0, 0);
      }
      __builtin_amdgcn_s_setprio(0);

      bf16x8 pf00, pf01;
      smpack(sv0, pf00, pf01);

      __builtin_amdgcn_s_setprio(1);
#pragma unroll
      for (int db = 0; db < 4; db++) {
        bf16x8 vf0 = *(const bf16x8*)(vt + db * 2304);          // keys [8lh..8lh+7]
        bf16x8 vf1 = *(const bf16x8*)(vt + db * 2304 + 16);     // keys [16+8lh..]
        o[db] = __builtin_amdgcn_mfma_f32_32x32x16_bf16(vf0, pf00, o[db], 0, 0, 0);
        o[db] = __builtin_amdgcn_mfma_f32_32x32x16_bf16(vf1, pf01, o[db], 0, 0, 0);
      }
      __builtin_amdgcn_s_setprio(0);
    }

    // ---- kb1: QK1 -> SM1 -> PV1 ----
    {
      f32x16 sv1;
#pragma unroll
      for (int r = 0; r < 16; r++) sv1[r] = 0.f;
      __builtin_amdgcn_s_setprio(1);
#pragma unroll
      for (int st = 0; st < 12; st++) {
        bf16x8 af = *(const bf16x8*)(Kb + (32 + ln) * 200 + st * 16 + lh * 8);
        sv1 = __builtin_amdgcn_mfma_f32_32x32x16_bf16(af, qf[st], sv1, 0, 0, 0);
      }
      __builtin_amdgcn_s_setprio(0);

      bf16x8 pf10, pf11;
      smpack(sv1, pf10, pf11);

      __builtin_amdgcn_s_setprio(1);
#pragma unroll
      for (int db = 0; db < 4; db++) {
        bf16x8 vf0 = *(const bf16x8*)(vt + db * 2304 + 32);
        bf16x8 vf1 = *(const bf16x8*)(vt + db * 2304 + 48);
        o[db] = __builtin_amdgcn_mfma_f32_32x32x16_bf16(vf0, pf10, o[db], 0, 0, 0);
        o[db] = __builtin_amdgcn_mfma_f32_32x32x16_bf16(vf1, pf11, o[db], 0, 0, 0);
      }
      __builtin_amdgcn_s_setprio(0);
    }

    cur ^= 1;
  }

  float lsum = ps + __shfl_xor(ps, 32, 64);
  const int s = qrow0 + ln;
  const size_t rbase = ((size_t)((z * 16 + h) * 2048) + s) * 128;
#pragma unroll
  for (int db = 0; db < 4; db++)
#pragma unroll
    for (int rq = 0; rq < 4; rq++) {
      ushort4 v4;
      v4.x = f2h(o[db][rq * 4 + 0] * 0.0625f);   // /16 safety scale vs fp16 range
      v4.y = f2h(o[db][rq * 4 + 1] * 0.0625f);
      v4.z = f2h(o[db][rq * 4 + 2] * 0.0625f);
      v4.w = f2h(o[db][rq * 4 + 3] * 0.0625f);
      *(ushort4*)(&opart[rbase + db * 32 + 8 * rq + 4 * lh]) = v4;
    }
  if (lh == 0) ml[(size_t)(z * 16 + h) * 2048 + s] = lsum;
}

// ---------------- reduction: fp16 partials (x16 descale) -> fp16 attn (z=3) ----------------
__global__ __launch_bounds__(256) void attn_reduce(const ush* __restrict__ opart,
                                                   const float* __restrict__ ml,
                                                   ush* __restrict__ attnh) {
  int row = blockIdx.x * 4 + (threadIdx.x >> 6);
  int l = threadIdx.x & 63;
  int h = row >> 11, s = row & 2047;
  float lsum = 0.f;
#pragma unroll
  for (int z = 0; z < 3; z++) lsum += ml[(size_t)(z * 16 + h) * 2048 + s];
  float inv = 16.0f / lsum;
#pragma unroll
  for (int c0 = 0; c0 < 128; c0 += 64) {
    int c = c0 + l;
    float acc = 0.f;
#pragma unroll
    for (int z = 0; z < 3; z++)
      acc += h2f(opart[((size_t)(z * 16 + h) * 2048 + s) * 128 + c]);
    attnh[(size_t)s * 2048 + h * 128 + c] = f2h(bf2f(f2bf(acc * inv)));
  }
}

// ---------------- launch ----------------
extern "C" void kernel_launch(void* const* d_in, const int* in_sizes, int n_in,
                              void* d_out, int out_size, void* d_ws, size_t ws_size,
                              hipStream_t stream) {
  const float* x        = (const float*)d_in[0];
  const float* wq_down  = (const float*)d_in[1];
  const float* wq_up    = (const float*)d_in[2];
  const float* wq_rope  = (const float*)d_in[3];
  const float* wkv_down = (const float*)d_in[4];
  const float* wkv_up   = (const float*)d_in[5];
  const float* wk_rope  = (const float*)d_in[6];
  const float* wo       = (const float*)d_in[7];
  char* ws = (char*)d_ws;

  size_t off = 0;
  auto alloc = [&](size_t b) { size_t c = off; off += (b + 255) & ~(size_t)255; return c; };
  const size_t XH    = alloc(2048UL * 2048 * 2);      // x fp16 (aliased by ATTNH later)
  const size_t WDH   = alloc(1152UL * 2048 * 2);
  const size_t KRL   = alloc(2048UL * 64 * 4);
  const size_t CQH   = alloc(2048UL * 512 * 2);
  const size_t CKVH  = alloc(2048UL * 512 * 2);
  const size_t WQH   = alloc(3072UL * 512 * 2);
  const size_t QUPF  = alloc(2048UL * 3072 * 2);
  const size_t WKVUH = alloc(4096UL * 512 * 2);
  const size_t WOH   = alloc(2048UL * 2048 * 2);
  const size_t KVF   = alloc(2048UL * 4096 * 2);
  const size_t QB    = alloc(16UL * 2048 * 192 * 2);
  const size_t KBT   = alloc(16UL * 32 * 12800 * 2);
  const size_t VTT   = alloc(16UL * 32 * 9216 * 2);
  const size_t TAB   = alloc(2048UL * 32 * 4 * 2);
  const size_t OPART = alloc(3UL * 16 * 2048 * 128 * 2);  // fp16 partials (z=3)
  const size_t ML    = alloc(3UL * 16 * 2048 * 4);
  const size_t ATTNH = XH;  // x fp16 dead after down-proj

  mega_pack<<<dim3(56576), 256, 0, stream>>>(
      wq_down, wkv_down, wk_rope, wq_up, wq_rope, wkv_up, wo, x,
      (ush*)(ws + WDH), (ush*)(ws + WQH), (ush*)(ws + WKVUH),
      (ush*)(ws + WOH), (ush*)(ws + XH), (float*)(ws + TAB));

  // down: (2048x2048)*(1152x2048)^T -> fp16 cq/ckv + f32 krl
  gemm_down<<<dim3(18, 32), 256, 0, stream>>>(
      (ush*)(ws + XH), (ush*)(ws + WDH),
      (ush*)(ws + CQH), (ush*)(ws + CKVH), (float*)(ws + KRL));

  // merged q-up + kv-up (one launch, 1792 blocks)
  gemm_up<<<dim3(112, 16), 256, 0, stream>>>(
      (ush*)(ws + CQH), (ush*)(ws + WQH),
      (ush*)(ws + CKVH), (ush*)(ws + WKVUH),
      (ush*)(ws + QUPF), (ush*)(ws + KVF));

  // builders + vtrans merged
  build_all<<<dim3(50688), 256, 0, stream>>>(
      (const ush*)(ws + QUPF), (const ush*)(ws + KVF), (const float*)(ws + KRL),
      (const float*)(ws + TAB), (ush*)(ws + QB), (ush*)(ws + KBT), (ush*)(ws + VTT));

  // attn: 768 blocks (16 qx x 16 h x z=3), 256 threads (4 waves), 3 blocks/CU
  attn_fused<<<dim3(16, 16, 3), 256, 0, stream>>>(
      (ush*)(ws + QB), (ush*)(ws + KBT), (ush*)(ws + VTT),
      (ush*)(ws + OPART), (float*)(ws + ML));
  attn_reduce<<<dim3(8192), 256, 0, stream>>>((const ush*)(ws + OPART), (const float*)(ws + ML),
                                              (ush*)(ws + ATTNH));

  // out: (2048x2048)*(2048x2048)^T -> d_out f32
  gemm_out<<<dim3(32, 16), 256, 0, stream>>>(
      (ush*)(ws + ATTNH), (ush*)(ws + WOH), (float*)d_out, 2048, 2048);
}

// Round 10
// 312.538 us; speedup vs baseline: 1.0269x; 1.0269x over previous
//
#include <hip/hip_runtime.h>
#include <stdint.h>
#include <math.h>

#define S_LEN 2048
#define NH 16

typedef __attribute__((ext_vector_type(8))) short bf16x8;
typedef __attribute__((ext_vector_type(4))) float f32x4;
typedef __attribute__((ext_vector_type(16))) float f32x16;
typedef unsigned short ush;

__device__ __forceinline__ ush f2bf(float f) {   // RNE float->bf16
  union { float f; unsigned u; } v; v.f = f;
  unsigned x = v.u;
  return (ush)((x + 0x7fffu + ((x >> 16) & 1u)) >> 16);
}
__device__ __forceinline__ float bf2f(ush b) {
  union { unsigned u; float f; } v; v.u = ((unsigned)b) << 16;
  return v.f;
}
__device__ __forceinline__ ush f2h(float f) {    // RNE float->fp16
  _Float16 h = (_Float16)f;
  union { _Float16 h; ush u; } v; v.h = h;
  return v.u;
}
__device__ __forceinline__ float h2f(ush u) {
  union { ush u; _Float16 h; } v; v.u = u;
  return (float)v.h;
}

// async global->LDS, 16B/lane; LDS dest = wave-uniform base + lane*16
__device__ __forceinline__ void gload_lds16(const ush* g, ush* l) {
  __builtin_amdgcn_global_load_lds((const __attribute__((address_space(1))) void*)g,
                                   (__attribute__((address_space(3))) void*)l, 16, 0, 0);
}

// ---------------- mega pack: all weights + x (fp16) + rope table, ONE launch ----------------
__global__ void mega_pack(const float* __restrict__ wq_down, const float* __restrict__ wkv_down,
                          const float* __restrict__ wk_rope, const float* __restrict__ wq_up,
                          const float* __restrict__ wq_rope, const float* __restrict__ wkv_up,
                          const float* __restrict__ wo, const float* __restrict__ x,
                          ush* __restrict__ wdh, ush* __restrict__ wqh, ush* __restrict__ wkvuh,
                          ush* __restrict__ woh, ush* __restrict__ xh, float* __restrict__ tab) {
  int idx = blockIdx.x * 256 + threadIdx.x;
  if (idx < 2359296) {  // fused down weights [wq_down|wkv_down|wk_rope|0] 1152x2048
    int r = idx >> 11, c = idx & 2047;
    float v = (r < 512) ? wq_down[(size_t)r * 2048 + c]
            : (r < 1024) ? wkv_down[(size_t)(r - 512) * 2048 + c]
            : (r < 1088) ? wk_rope[(size_t)(r - 1024) * 2048 + c] : 0.f;
    wdh[idx] = f2h(v);
    return;
  }
  idx -= 2359296;
  if (idx < 1572864) {  // fused [wq_up|wq_rope] 3072x512
    int r = idx >> 9, c = idx & 511;
    float v = (r < 2048) ? wq_up[(size_t)r * 512 + c] : wq_rope[(size_t)(r - 2048) * 512 + c];
    wqh[idx] = f2h(v);
    return;
  }
  idx -= 1572864;
  if (idx < 2097152) { wkvuh[idx] = f2h(wkv_up[idx]); return; }   // 4096x512
  idx -= 2097152;
  if (idx < 4194304) { woh[idx] = f2h(wo[idx]); return; }         // 2048x2048
  idx -= 4194304;
  if (idx < 4194304) { xh[idx] = f2h(x[idx]); return; }           // 2048x2048
  idx -= 4194304;
  if (idx < 65536) {  // rope table
    int tt = idx >> 5, i = idx & 31;
    float inv_freq = 1.0f / powf(10000.0f, (float)i * (1.0f / 32.0f));
    float fr = (float)tt * inv_freq;
    tab[idx] = sinf(fr);
    tab[65536 + idx] = cosf(fr);
  }
}

// ---------------- down GEMM BM=64,BN=64, single-barrier dbuf, fused epilogue ----------------
__global__ __launch_bounds__(256) void gemm_down(
    const ush* __restrict__ A, const ush* __restrict__ B,
    ush* __restrict__ cqh, ush* __restrict__ ckvh, float* __restrict__ krl) {
  constexpr int K = 2048;
  __shared__ __align__(16) ush As[2 * 64 * 32];
  __shared__ __align__(16) ush Bs[2 * 64 * 32];
  const int t = threadIdx.x, l = t & 63, w = t >> 6;
  const int wm = w & 1, wn = w >> 1;
  const int m0 = blockIdx.y * 64, n0 = blockIdx.x * 64;
  const int lm = l & 15, lq = l >> 4;
  const int lr = l >> 2, lc = (l & 3) * 8;

  f32x4 acc[2][2];
  const f32x4 zero = {0.f, 0.f, 0.f, 0.f};
#pragma unroll
  for (int i = 0; i < 2; i++)
#pragma unroll
    for (int j = 0; j < 2; j++) acc[i][j] = zero;

  const ush* Ag = A + (size_t)(m0 + w * 16 + lr) * K + lc;
  const ush* Bg = B + (size_t)(n0 + w * 16 + lr) * K + lc;

  // prologue stage k=0 -> buf0
  gload_lds16(Ag, As + w * 512);
  gload_lds16(Bg, Bs + w * 512);

  int cur = 0;
  for (int k0 = 0; k0 < K; k0 += 32) {
    asm volatile("s_waitcnt vmcnt(0)" ::: "memory");
    __builtin_amdgcn_s_barrier();
    __builtin_amdgcn_sched_barrier(0);
    if (k0 + 32 < K) {
      int nb = cur ^ 1;
      gload_lds16(Ag + k0 + 32, As + nb * 2048 + w * 512);
      gload_lds16(Bg + k0 + 32, Bs + nb * 2048 + w * 512);
    }
    __builtin_amdgcn_sched_barrier(0);
    const ush* Asc = As + cur * 2048;
    const ush* Bsc = Bs + cur * 2048;
    bf16x8 af[2], bfr[2];
#pragma unroll
    for (int i = 0; i < 2; i++)
      af[i] = *(const bf16x8*)(Asc + (wm * 32 + i * 16 + lm) * 32 + lq * 8);
#pragma unroll
    for (int j = 0; j < 2; j++)
      bfr[j] = *(const bf16x8*)(Bsc + (wn * 32 + j * 16 + lm) * 32 + lq * 8);
#pragma unroll
    for (int i = 0; i < 2; i++)
#pragma unroll
      for (int j = 0; j < 2; j++)
        acc[i][j] = __builtin_amdgcn_mfma_f32_16x16x32_f16(af[i], bfr[j], acc[i][j], 0, 0, 0);
    cur ^= 1;
  }

#pragma unroll
  for (int i = 0; i < 2; i++)
#pragma unroll
    for (int j = 0; j < 2; j++)
#pragma unroll
      for (int r = 0; r < 4; r++) {
        int mm = m0 + wm * 32 + i * 16 + lq * 4 + r;
        int nn = n0 + wn * 32 + j * 16 + lm;
        float v = acc[i][j][r];
        if (nn < 512)       cqh[(size_t)mm * 512 + nn] = f2h(v);
        else if (nn < 1024) ckvh[(size_t)mm * 512 + nn - 512] = f2h(v);
        else if (nn < 1088) krl[(size_t)mm * 64 + nn - 1024] = v;
      }
}

// ---------------- merged up GEMM (qup blocks [0,24), kvup [24,56)): BM=128,BN=128,K=512,
// single-barrier dbuf, 4x4 frag (m93/m97-proven tile), fp16 out ----------------
__global__ __launch_bounds__(256) void gemm_up(
    const ush* __restrict__ cqh, const ush* __restrict__ wqh,
    const ush* __restrict__ ckvh, const ush* __restrict__ wkvuh,
    ush* __restrict__ qupf, ush* __restrict__ kvf) {
  constexpr int K = 512, FI = 4, FJ = 4;
  __shared__ __align__(16) ush As[2 * 128 * 32];
  __shared__ __align__(16) ush Bs[2 * 128 * 32];
  int bx = blockIdx.x;
  const ush* A; const ush* B; ush* C; int ldc;
  if (bx < 24) { A = cqh; B = wqh; C = qupf; ldc = 3072; }
  else { bx -= 24; A = ckvh; B = wkvuh; C = kvf; ldc = 4096; }
  const int t = threadIdx.x, l = t & 63, w = t >> 6;
  const int wm = w & 1, wn = w >> 1;
  const int m0 = blockIdx.y * 128, n0 = bx * 128;
  const int lm = l & 15, lq = l >> 4;
  const int lr = l >> 2, lc = (l & 3) * 8;

  f32x4 acc[FI][FJ];
  const f32x4 zero = {0.f, 0.f, 0.f, 0.f};
#pragma unroll
  for (int i = 0; i < FI; i++)
#pragma unroll
    for (int j = 0; j < FJ; j++) acc[i][j] = zero;

  const ush* Ag[2]; const ush* Bg[2];
#pragma unroll
  for (int i = 0; i < 2; i++) {
    Ag[i] = A + (size_t)(m0 + w * 32 + i * 16 + lr) * K + lc;
    Bg[i] = B + (size_t)(n0 + w * 32 + i * 16 + lr) * K + lc;
  }

#pragma unroll
  for (int i = 0; i < 2; i++) {
    gload_lds16(Ag[i], As + w * 1024 + i * 512);
    gload_lds16(Bg[i], Bs + w * 1024 + i * 512);
  }

  int cur = 0;
  for (int k0 = 0; k0 < K; k0 += 32) {
    asm volatile("s_waitcnt vmcnt(0)" ::: "memory");
    __builtin_amdgcn_s_barrier();
    __builtin_amdgcn_sched_barrier(0);
    if (k0 + 32 < K) {
      int nb = cur ^ 1;
#pragma unroll
      for (int i = 0; i < 2; i++) {
        gload_lds16(Ag[i] + k0 + 32, As + nb * 4096 + w * 1024 + i * 512);
        gload_lds16(Bg[i] + k0 + 32, Bs + nb * 4096 + w * 1024 + i * 512);
      }
    }
    __builtin_amdgcn_sched_barrier(0);
    const ush* Asc = As + cur * 4096;
    const ush* Bsc = Bs + cur * 4096;
    bf16x8 af[FI], bfr[FJ];
#pragma unroll
    for (int i = 0; i < FI; i++)
      af[i] = *(const bf16x8*)(Asc + (wm * 64 + i * 16 + lm) * 32 + lq * 8);
#pragma unroll
    for (int j = 0; j < FJ; j++)
      bfr[j] = *(const bf16x8*)(Bsc + (wn * 64 + j * 16 + lm) * 32 + lq * 8);
#pragma unroll
    for (int i = 0; i < FI; i++)
#pragma unroll
      for (int j = 0; j < FJ; j++)
        acc[i][j] = __builtin_amdgcn_mfma_f32_16x16x32_f16(af[i], bfr[j], acc[i][j], 0, 0, 0);
    cur ^= 1;
  }

#pragma unroll
  for (int i = 0; i < FI; i++)
#pragma unroll
    for (int j = 0; j < FJ; j++)
#pragma unroll
      for (int r = 0; r < 4; r++) {
        int mm = m0 + wm * 64 + i * 16 + lq * 4 + r;
        int nn = n0 + wn * 64 + j * 16 + lm;
        C[(size_t)mm * ldc + nn] = f2h(acc[i][j][r]);
      }
}

// ---------------- out GEMM: BM=128,BN=128, single-barrier dbuf, 4x4 frag, f32 out ----------------
__global__ __launch_bounds__(256) void gemm_out(
    const ush* __restrict__ A, const ush* __restrict__ B, float* __restrict__ C,
    int K, int ldc) {
  constexpr int FI = 4, FJ = 4;
  __shared__ __align__(16) ush As[2 * 128 * 32];
  __shared__ __align__(16) ush Bs[2 * 128 * 32];
  const int t = threadIdx.x, l = t & 63, w = t >> 6;
  const int wm = w & 1, wn = w >> 1;
  const int m0 = blockIdx.y * 128, n0 = blockIdx.x * 128;
  const int lm = l & 15, lq = l >> 4;
  const int lr = l >> 2, lc = (l & 3) * 8;

  f32x4 acc[FI][FJ];
  const f32x4 zero = {0.f, 0.f, 0.f, 0.f};
#pragma unroll
  for (int i = 0; i < FI; i++)
#pragma unroll
    for (int j = 0; j < FJ; j++) acc[i][j] = zero;

  const ush* Ag[2]; const ush* Bg[2];
#pragma unroll
  for (int i = 0; i < 2; i++) {
    Ag[i] = A + (size_t)(m0 + w * 32 + i * 16 + lr) * K + lc;
    Bg[i] = B + (size_t)(n0 + w * 32 + i * 16 + lr) * K + lc;
  }

#pragma unroll
  for (int i = 0; i < 2; i++) {
    gload_lds16(Ag[i], As + w * 1024 + i * 512);
    gload_lds16(Bg[i], Bs + w * 1024 + i * 512);
  }

  int cur = 0;
  for (int k0 = 0; k0 < K; k0 += 32) {
    asm volatile("s_waitcnt vmcnt(0)" ::: "memory");
    __builtin_amdgcn_s_barrier();
    __builtin_amdgcn_sched_barrier(0);
    if (k0 + 32 < K) {
      int nb = cur ^ 1;
#pragma unroll
      for (int i = 0; i < 2; i++) {
        gload_lds16(Ag[i] + k0 + 32, As + nb * 4096 + w * 1024 + i * 512);
        gload_lds16(Bg[i] + k0 + 32, Bs + nb * 4096 + w * 1024 + i * 512);
      }
    }
    __builtin_amdgcn_sched_barrier(0);
    const ush* Asc = As + cur * 4096;
    const ush* Bsc = Bs + cur * 4096;
    bf16x8 af[FI], bfr[FJ];
#pragma unroll
    for (int i = 0; i < FI; i++)
      af[i] = *(const bf16x8*)(Asc + (wm * 64 + i * 16 + lm) * 32 + lq * 8);
#pragma unroll
    for (int j = 0; j < FJ; j++)
      bfr[j] = *(const bf16x8*)(Bsc + (wn * 64 + j * 16 + lm) * 32 + lq * 8);
#pragma unroll
    for (int i = 0; i < FI; i++)
#pragma unroll
      for (int j = 0; j < FJ; j++)
        acc[i][j] = __builtin_amdgcn_mfma_f32_16x16x32_f16(af[i], bfr[j], acc[i][j], 0, 0, 0);
    cur ^= 1;
  }

#pragma unroll
  for (int i = 0; i < FI; i++)
#pragma unroll
    for (int j = 0; j < FJ; j++)
#pragma unroll
      for (int r = 0; r < 4; r++) {
        int mm = m0 + wm * 64 + i * 16 + lq * 4 + r;
        int nn = n0 + wn * 64 + j * 16 + lm;
        C[(size_t)mm * ldc + nn] = acc[i][j][r];
      }
}

// ---------------- builders: qb(scale-folded) + padded-tiled kbt + vtrans (merged) ----------------
__global__ void build_all(const ush* __restrict__ qupf, const ush* __restrict__ kvf,
                          const float* __restrict__ krl, const float* __restrict__ tab,
                          ush* __restrict__ qb, ush* __restrict__ kbt, ush* __restrict__ vtt) {
  const float scale = 0.07216878364870323f;  // 1/sqrt(192), folded into q
  if (blockIdx.x >= 50176) {  // vtrans: (s,d) fp16 -> (h,T,d[128],c[72]) bf16
    __shared__ ush Vt[128 * 72];
    int b = blockIdx.x - 50176;
    const int T = b & 31, h = b >> 5, t = threadIdx.x;
    const int key = t >> 5, d0 = (t & 31) * 4;
#pragma unroll
    for (int pass = 0; pass < 8; ++pass) {
      int k = key + pass * 8;
      int s = T * 64 + k;
      ushort4 v = *(const ushort4*)(kvf + (size_t)s * 4096 + 2048 + h * 128 + d0);
      Vt[(d0 + 0) * 72 + k] = f2bf(h2f(v.x));
      Vt[(d0 + 1) * 72 + k] = f2bf(h2f(v.y));
      Vt[(d0 + 2) * 72 + k] = f2bf(h2f(v.z));
      Vt[(d0 + 3) * 72 + k] = f2bf(h2f(v.w));
    }
    __syncthreads();
    ush* dst = vtt + (size_t)(h * 32 + T) * 9216;
    for (int off = t; off < 1152; off += 256) {
      int row = off / 9, c8 = (off % 9) * 8;
      *(bf16x8*)(dst + row * 72 + c8) = *(const bf16x8*)(Vt + row * 72 + c8);
    }
    return;
  }
  int idx = blockIdx.x * 256 + threadIdx.x;
  if (idx < 6291456) {  // qb (h,s,192), pre-scaled
    int d = idx % 192; int sh = idx / 192; int h = sh & 15; int s = sh >> 4;
    ush v;
    if (d < 128) {
      v = f2bf(h2f(qupf[(size_t)s * 3072 + h * 128 + d]) * scale);
    } else {
      int r = d - 128, i = r & 31;
      float sn = tab[s * 32 + i], cs = tab[65536 + s * 32 + i];
      const ush* qr = qupf + (size_t)s * 3072 + 2048 + h * 64;
      float xv = h2f(qr[r]);
      float other = (r < 32) ? -h2f(qr[r + 32]) : h2f(qr[r - 32]);
      v = f2bf((xv * cs + other * sn) * scale);
    }
    qb[((size_t)h * S_LEN + s) * 192 + d] = v;
    return;
  }
  idx -= 6291456;
  if (idx < 6553600) {  // kbt (h,T,key[64],c[200])
    int c = idx % 200; int r2 = idx / 200;
    int key = r2 & 63; int r3 = r2 >> 6; int T = r3 & 31; int h = r3 >> 5;
    int s = T * 64 + key;
    ush v = 0;
    if (c < 128) {
      v = f2bf(h2f(kvf[(size_t)s * 4096 + h * 128 + c]));
    } else if (c < 192) {
      int r = c - 128, i = r & 31;
      float sn = tab[s * 32 + i], cs = tab[65536 + s * 32 + i];
      const float* kr = krl + (size_t)s * 64;
      float xv = kr[r];
      float other = (r < 32) ? -kr[r + 32] : kr[r - 32];
      v = f2bf(xv * cs + other * sn);
    }
    kbt[((size_t)(h * 32 + T) * 64 + key) * 200 + c] = v;
  }
}

// ---------------- flash attention v9: R3 structure (8-wave, K+V dbuf LDS 88KB, single
// barrier/iter, full-iter prefetch) + SPLIT QK accumulator chains (2 independent MFMA
// chains per kb -> halved dependent latency), z=2, __expf, permlane32_swap ----------------
__global__ __launch_bounds__(512, 2) void attn_fused(
    const ush* __restrict__ qb, const ush* __restrict__ kbt, const ush* __restrict__ vtt,
    ush* __restrict__ opart, float* __restrict__ ml) {
  __shared__ __align__(16) ush Ks[2][64 * 200];   // 2 x 25.6 KB
  __shared__ __align__(16) ush Vs[2][128 * 72];   // 2 x 18.4 KB  (88 KB total)
  const int t = threadIdx.x, l = t & 63, w = t >> 6;   // 8 waves
  const int id = blockIdx.x + 8 * (blockIdx.y + 16 * blockIdx.z);
  const int wid = (id & 7) * 32 + (id >> 3);
  const int qx = wid & 7, h = (wid >> 3) & 15, z = wid >> 7;
  const int qrow0 = qx * 256 + w * 32;
  const int ln = l & 31, lh = l >> 5;

  bf16x8 qf[12];
#pragma unroll
  for (int st = 0; st < 12; st++)
    qf[st] = *(const bf16x8*)(qb + ((size_t)h * S_LEN + qrow0 + ln) * 192 + st * 16 + lh * 8);
#pragma unroll
  for (int st = 0; st < 12; st++) asm volatile("" : "+v"(qf[st]));

  f32x16 o[4];
#pragma unroll
  for (int i = 0; i < 4; i++)
#pragma unroll
    for (int r = 0; r < 16; r++) o[i][r] = 0.f;
  float ps = 0.f;  // per-lane sum of exp; partner lane (l^32) holds other half

  const ush* kbase = kbt + (size_t)(h * 32 + z * 16) * 12800;
  const ush* vbase = vtt + (size_t)(h * 32 + z * 16) * 9216;

  // softmax pack: sv (16 scores) -> exp -> bf16 pairs -> lane^32 half-exchange
  auto smpack = [&ps](const f32x16& svv, bf16x8& f0, bf16x8& f1) {
    unsigned pk8[8];
#pragma unroll
    for (int g = 0; g < 4; g++) {
      float p0 = __expf(svv[4 * g + 0]);   // scale pre-folded into q
      float p1 = __expf(svv[4 * g + 1]);
      float p2 = __expf(svv[4 * g + 2]);
      float p3 = __expf(svv[4 * g + 3]);
      ps += (p0 + p1) + (p2 + p3);
      unsigned lo, hi;
      asm("v_cvt_pk_bf16_f32 %0, %1, %2" : "=v"(lo) : "v"(p0), "v"(p1));
      asm("v_cvt_pk_bf16_f32 %0, %1, %2" : "=v"(hi) : "v"(p2), "v"(p3));
      pk8[2 * g] = lo; pk8[2 * g + 1] = hi;
    }
    asm("v_permlane32_swap_b32 %0, %1" : "+v"(pk8[0]), "+v"(pk8[2]));
    asm("v_permlane32_swap_b32 %0, %1" : "+v"(pk8[1]), "+v"(pk8[3]));
    asm("v_permlane32_swap_b32 %0, %1" : "+v"(pk8[4]), "+v"(pk8[6]));
    asm("v_permlane32_swap_b32 %0, %1" : "+v"(pk8[5]), "+v"(pk8[7]));
    union { unsigned d[4]; bf16x8 v; } u0, u1;
    u0.d[0] = pk8[0]; u0.d[1] = pk8[1]; u0.d[2] = pk8[2]; u0.d[3] = pk8[3];
    u1.d[0] = pk8[4]; u1.d[1] = pk8[5]; u1.d[2] = pk8[6]; u1.d[3] = pk8[7];
    f0 = u0.v; f1 = u1.v;
  };

  // split-chain QK: two independent accumulator chains (st 0..5 and 6..11), summed at end
  auto qkhalf = [&](const ush* Kb, int rowoff, f32x16& sv) {
    f32x16 sva, svb;
#pragma unroll
    for (int r = 0; r < 16; r++) { sva[r] = 0.f; svb[r] = 0.f; }
    __builtin_amdgcn_s_setprio(1);
#pragma unroll
    for (int st = 0; st < 6; st++) {
      bf16x8 af0 = *(const bf16x8*)(Kb + (rowoff + ln) * 200 + st * 16 + lh * 8);
      bf16x8 af1 = *(const bf16x8*)(Kb + (rowoff + ln) * 200 + (st + 6) * 16 + lh * 8);
      sva = __builtin_amdgcn_mfma_f32_32x32x16_bf16(af0, qf[st], sva, 0, 0, 0);
      svb = __builtin_amdgcn_mfma_f32_32x32x16_bf16(af1, qf[st + 6], svb, 0, 0, 0);
    }
    __builtin_amdgcn_s_setprio(0);
#pragma unroll
    for (int r = 0; r < 16; r++) sv[r] = sva[r] + svb[r];
  };

  // prologue: stage tile 0 into buf 0 (43 chunks of 1 KB over 8 waves)
  for (int c = w; c < 43; c += 8) {
    if (c < 25) gload_lds16(kbase + c * 512 + l * 8, &Ks[0][c * 512]);
    else        gload_lds16(vbase + (c - 25) * 512 + l * 8, &Vs[0][(c - 25) * 512]);
  }

  int cur = 0;
  for (int it = 0; it < 16; ++it) {
    // drain own loads for tile it (issued a full iteration ago), then publish
    asm volatile("s_waitcnt vmcnt(0)" ::: "memory");
    __builtin_amdgcn_s_barrier();
    __builtin_amdgcn_sched_barrier(0);
    // issue next-tile prefetch AFTER the barrier; stays in flight under this iter's compute
    if (it < 15) {
      const ush* ksrc = kbase + (size_t)(it + 1) * 12800;
      const ush* vsrc = vbase + (size_t)(it + 1) * 9216;
      ush* kd = &Ks[cur ^ 1][0];
      ush* vd = &Vs[cur ^ 1][0];
      for (int c = w; c < 43; c += 8) {
        if (c < 25) gload_lds16(ksrc + c * 512 + l * 8, kd + c * 512);
        else        gload_lds16(vsrc + (c - 25) * 512 + l * 8, vd + (c - 25) * 512);
      }
    }
    __builtin_amdgcn_sched_barrier(0);

    const ush* Kb = &Ks[cur][0];
    const ush* Vb = &Vs[cur][0];

    // QK kb0 (split chains)
    f32x16 sv0;
    qkhalf(Kb, 0, sv0);

    // SM kb0 (VALU) — overlaps QK kb1 (MFMA)
    bf16x8 pf00, pf01;
    smpack(sv0, pf00, pf01);

    // QK kb1 (split chains)
    f32x16 sv1;
    qkhalf(Kb, 32, sv1);

    // PV kb0
    __builtin_amdgcn_s_setprio(1);
#pragma unroll
    for (int db = 0; db < 4; db++) {
      bf16x8 vf0 = *(const bf16x8*)(Vb + (db * 32 + ln) * 72 + lh * 8);
      bf16x8 vf1 = *(const bf16x8*)(Vb + (db * 32 + ln) * 72 + 16 + lh * 8);
      o[db] = __builtin_amdgcn_mfma_f32_32x32x16_bf16(vf0, pf00, o[db], 0, 0, 0);
      o[db] = __builtin_amdgcn_mfma_f32_32x32x16_bf16(vf1, pf01, o[db], 0, 0, 0);
    }
    __builtin_amdgcn_s_setprio(0);

    // SM kb1
    bf16x8 pf10, pf11;
    smpack(sv1, pf10, pf11);

    // PV kb1
    __builtin_amdgcn_s_setprio(1);
#pragma unroll
    for (int db = 0; db < 4; db++) {
      bf16x8 vf0 = *(const bf16x8*)(Vb + (db * 32 + ln) * 72 + 32 + lh * 8);
      bf16x8 vf1 = *(const bf16x8*)(Vb + (db * 32 + ln) * 72 + 48 + lh * 8);
      o[db] = __builtin_amdgcn_mfma_f32_32x32x16_bf16(vf0, pf10, o[db], 0, 0, 0);
      o[db] = __builtin_amdgcn_mfma_f32_32x32x16_bf16(vf1, pf11, o[db], 0, 0, 0);
    }
    __builtin_amdgcn_s_setprio(0);

    cur ^= 1;
  }

  float lsum = ps + __shfl_xor(ps, 32, 64);
  const int s = qrow0 + ln;
  const size_t rbase = ((size_t)((z * 16 + h) * 2048) + s) * 128;
#pragma unroll
  for (int db = 0; db < 4; db++)
#pragma unroll
    for (int rq = 0; rq < 4; rq++) {
      ushort4 v4;
      v4.x = f2h(o[db][rq * 4 + 0] * 0.0625f);   // /16 safety scale vs fp16 range
      v4.y = f2h(o[db][rq * 4 + 1] * 0.0625f);
      v4.z = f2h(o[db][rq * 4 + 2] * 0.0625f);
      v4.w = f2h(o[db][rq * 4 + 3] * 0.0625f);
      *(ushort4*)(&opart[rbase + db * 32 + 8 * rq + 4 * lh]) = v4;
    }
  if (lh == 0) ml[(size_t)(z * 16 + h) * 2048 + s] = lsum;
}

// ---------------- reduction: fp16 partials (x16 descale) -> fp16 attn (z=2) ----------------
__global__ __launch_bounds__(256) void attn_reduce(const ush* __restrict__ opart,
                                                   const float* __restrict__ ml,
                                                   ush* __restrict__ attnh) {
  int row = blockIdx.x * 4 + (threadIdx.x >> 6);
  int l = threadIdx.x & 63;
  int h = row >> 11, s = row & 2047;
  float lsum = 0.f;
#pragma unroll
  for (int z = 0; z < 2; z++) lsum += ml[(size_t)(z * 16 + h) * 2048 + s];
  float inv = 16.0f / lsum;
#pragma unroll
  for (int c0 = 0; c0 < 128; c0 += 64) {
    int c = c0 + l;
    float acc = 0.f;
#pragma unroll
    for (int z = 0; z < 2; z++)
      acc += h2f(opart[((size_t)(z * 16 + h) * 2048 + s) * 128 + c]);
    attnh[(size_t)s * 2048 + h * 128 + c] = f2h(bf2f(f2bf(acc * inv)));
  }
}

// ---------------- launch ----------------
extern "C" void kernel_launch(void* const* d_in, const int* in_sizes, int n_in,
                              void* d_out, int out_size, void* d_ws, size_t ws_size,
                              hipStream_t stream) {
  const float* x        = (const float*)d_in[0];
  const float* wq_down  = (const float*)d_in[1];
  const float* wq_up    = (const float*)d_in[2];
  const float* wq_rope  = (const float*)d_in[3];
  const float* wkv_down = (const float*)d_in[4];
  const float* wkv_up   = (const float*)d_in[5];
  const float* wk_rope  = (const float*)d_in[6];
  const float* wo       = (const float*)d_in[7];
  char* ws = (char*)d_ws;

  size_t off = 0;
  auto alloc = [&](size_t b) { size_t c = off; off += (b + 255) & ~(size_t)255; return c; };
  const size_t XH    = alloc(2048UL * 2048 * 2);      // x fp16 (aliased by ATTNH later)
  const size_t WDH   = alloc(1152UL * 2048 * 2);
  const size_t KRL   = alloc(2048UL * 64 * 4);
  const size_t CQH   = alloc(2048UL * 512 * 2);
  const size_t CKVH  = alloc(2048UL * 512 * 2);
  const size_t WQH   = alloc(3072UL * 512 * 2);
  const size_t QUPF  = alloc(2048UL * 3072 * 2);
  const size_t WKVUH = alloc(4096UL * 512 * 2);
  const size_t WOH   = alloc(2048UL * 2048 * 2);
  const size_t KVF   = alloc(2048UL * 4096 * 2);
  const size_t QB    = alloc(16UL * 2048 * 192 * 2);
  const size_t KBT   = alloc(16UL * 32 * 12800 * 2);
  const size_t VTT   = alloc(16UL * 32 * 9216 * 2);
  const size_t TAB   = alloc(2048UL * 32 * 4 * 2);
  const size_t OPART = alloc(2UL * 16 * 2048 * 128 * 2);  // fp16 partials (z=2)
  const size_t ML    = alloc(2UL * 16 * 2048 * 4);
  const size_t ATTNH = XH;  // x fp16 dead after down-proj

  mega_pack<<<dim3(56576), 256, 0, stream>>>(
      wq_down, wkv_down, wk_rope, wq_up, wq_rope, wkv_up, wo, x,
      (ush*)(ws + WDH), (ush*)(ws + WQH), (ush*)(ws + WKVUH),
      (ush*)(ws + WOH), (ush*)(ws + XH), (float*)(ws + TAB));

  // down: (2048x2048)*(1152x2048)^T -> fp16 cq/ckv + f32 krl
  gemm_down<<<dim3(18, 32), 256, 0, stream>>>(
      (ush*)(ws + XH), (ush*)(ws + WDH),
      (ush*)(ws + CQH), (ush*)(ws + CKVH), (float*)(ws + KRL));

  // merged q-up + kv-up, 128x128 tiles (qup 24 blocks, kvup 32 blocks along x)
  gemm_up<<<dim3(56, 16), 256, 0, stream>>>(
      (ush*)(ws + CQH), (ush*)(ws + WQH),
      (ush*)(ws + CKVH), (ush*)(ws + WKVUH),
      (ush*)(ws + QUPF), (ush*)(ws + KVF));

  // builders + vtrans merged
  build_all<<<dim3(50688), 256, 0, stream>>>(
      (const ush*)(ws + QUPF), (const ush*)(ws + KVF), (const float*)(ws + KRL),
      (const float*)(ws + TAB), (ush*)(ws + QB), (ush*)(ws + KBT), (ush*)(ws + VTT));

  // attn: 256 blocks (8 qx x 16 h x z=2), 512 threads
  attn_fused<<<dim3(8, 16, 2), 512, 0, stream>>>(
      (ush*)(ws + QB), (ush*)(ws + KBT), (ush*)(ws + VTT),
      (ush*)(ws + OPART), (float*)(ws + ML));
  attn_reduce<<<dim3(8192), 256, 0, stream>>>((const ush*)(ws + OPART), (const float*)(ws + ML),
                                              (ush*)(ws + ATTNH));

  // out: (2048x2048)*(2048x2048)^T -> d_out f32, 128x128 tiles
  gemm_out<<<dim3(16, 16), 256, 0, stream>>>(
      (ush*)(ws + ATTNH), (ush*)(ws + WOH), (float*)d_out, 2048, 2048);
}

// Round 11
// 299.486 us; speedup vs baseline: 1.0717x; 1.0436x over previous
//
#include <hip/hip_runtime.h>
#include <stdint.h>
#include <math.h>

#define S_LEN 2048
#define NH 16

typedef __attribute__((ext_vector_type(8))) short bf16x8;
typedef __attribute__((ext_vector_type(4))) float f32x4;
typedef __attribute__((ext_vector_type(16))) float f32x16;
typedef unsigned short ush;

__device__ __forceinline__ ush f2bf(float f) {   // RNE float->bf16
  union { float f; unsigned u; } v; v.f = f;
  unsigned x = v.u;
  return (ush)((x + 0x7fffu + ((x >> 16) & 1u)) >> 16);
}
__device__ __forceinline__ float bf2f(ush b) {
  union { unsigned u; float f; } v; v.u = ((unsigned)b) << 16;
  return v.f;
}
__device__ __forceinline__ ush f2h(float f) {    // RNE float->fp16
  _Float16 h = (_Float16)f;
  union { _Float16 h; ush u; } v; v.h = h;
  return v.u;
}
__device__ __forceinline__ float h2f(ush u) {
  union { ush u; _Float16 h; } v; v.u = u;
  return (float)v.h;
}

// async global->LDS, 16B/lane; LDS dest = wave-uniform base + lane*16
__device__ __forceinline__ void gload_lds16(const ush* g, ush* l) {
  __builtin_amdgcn_global_load_lds((const __attribute__((address_space(1))) void*)g,
                                   (__attribute__((address_space(3))) void*)l, 16, 0, 0);
}

// ---------------- mega pack v2: float4-vectorized (4 elem/thread), ONE launch ----------------
__global__ void mega_pack(const float* __restrict__ wq_down, const float* __restrict__ wkv_down,
                          const float* __restrict__ wk_rope, const float* __restrict__ wq_up,
                          const float* __restrict__ wq_rope, const float* __restrict__ wkv_up,
                          const float* __restrict__ wo, const float* __restrict__ x,
                          ush* __restrict__ wdh, ush* __restrict__ wqh, ush* __restrict__ wkvuh,
                          ush* __restrict__ woh, ush* __restrict__ xh, float* __restrict__ tab) {
  int idx = blockIdx.x * 256 + threadIdx.x;
  if (idx < 3604480) {        // quad-converters: 14417920 f32 elements / 4
    int qi = idx * 4;
    if (qi < 2359296) {       // fused down weights [wq_down|wkv_down|wk_rope|0] 1152x2048
      int r = qi >> 11, c = qi & 2047;
      float4 v = {0.f, 0.f, 0.f, 0.f};
      if (r < 512)       v = *(const float4*)(wq_down + (size_t)r * 2048 + c);
      else if (r < 1024) v = *(const float4*)(wkv_down + (size_t)(r - 512) * 2048 + c);
      else if (r < 1088) v = *(const float4*)(wk_rope + (size_t)(r - 1024) * 2048 + c);
      ushort4 o4; o4.x = f2h(v.x); o4.y = f2h(v.y); o4.z = f2h(v.z); o4.w = f2h(v.w);
      *(ushort4*)(wdh + qi) = o4;
      return;
    }
    qi -= 2359296;
    if (qi < 1572864) {       // fused [wq_up|wq_rope] 3072x512
      int r = qi >> 9, c = qi & 511;
      const float* src = (r < 2048) ? wq_up + (size_t)r * 512 + c
                                    : wq_rope + (size_t)(r - 2048) * 512 + c;
      float4 v = *(const float4*)src;
      ushort4 o4; o4.x = f2h(v.x); o4.y = f2h(v.y); o4.z = f2h(v.z); o4.w = f2h(v.w);
      *(ushort4*)(wqh + qi) = o4;
      return;
    }
    qi -= 1572864;
    if (qi < 2097152) {       // wkv_up 4096x512
      float4 v = *(const float4*)(wkv_up + qi);
      ushort4 o4; o4.x = f2h(v.x); o4.y = f2h(v.y); o4.z = f2h(v.z); o4.w = f2h(v.w);
      *(ushort4*)(wkvuh + qi) = o4;
      return;
    }
    qi -= 2097152;
    if (qi < 4194304) {       // wo 2048x2048
      float4 v = *(const float4*)(wo + qi);
      ushort4 o4; o4.x = f2h(v.x); o4.y = f2h(v.y); o4.z = f2h(v.z); o4.w = f2h(v.w);
      *(ushort4*)(woh + qi) = o4;
      return;
    }
    qi -= 4194304;
    {                         // x 2048x2048
      float4 v = *(const float4*)(x + qi);
      ushort4 o4; o4.x = f2h(v.x); o4.y = f2h(v.y); o4.z = f2h(v.z); o4.w = f2h(v.w);
      *(ushort4*)(xh + qi) = o4;
      return;
    }
  }
  idx -= 3604480;
  if (idx < 65536) {  // rope table
    int tt = idx >> 5, i = idx & 31;
    float inv_freq = 1.0f / powf(10000.0f, (float)i * (1.0f / 32.0f));
    float fr = (float)tt * inv_freq;
    tab[idx] = sinf(fr);
    tab[65536 + idx] = cosf(fr);
  }
}

// ---------------- down GEMM v2: BM=128,BN=64,K=2048, single-barrier dbuf, fused epilogue ----------------
__global__ __launch_bounds__(256) void gemm_down(
    const ush* __restrict__ A, const ush* __restrict__ B,
    ush* __restrict__ cqh, ush* __restrict__ ckvh, float* __restrict__ krl) {
  constexpr int BM = 128, BN = 64, K = 2048, FI = 4, FJ = 2;
  __shared__ __align__(16) ush As[2 * BM * 32];
  __shared__ __align__(16) ush Bs[2 * BN * 32];
  const int t = threadIdx.x, l = t & 63, w = t >> 6;
  const int wm = w & 1, wn = w >> 1;
  const int m0 = blockIdx.y * BM, n0 = blockIdx.x * BN;
  const int lm = l & 15, lq = l >> 4;
  const int lr = l >> 2, lc = (l & 3) * 8;

  f32x4 acc[FI][FJ];
  const f32x4 zero = {0.f, 0.f, 0.f, 0.f};
#pragma unroll
  for (int i = 0; i < FI; i++)
#pragma unroll
    for (int j = 0; j < FJ; j++) acc[i][j] = zero;

  const ush* Ag[2];
#pragma unroll
  for (int i = 0; i < 2; i++) Ag[i] = A + (size_t)(m0 + w * 32 + i * 16 + lr) * K + lc;
  const ush* Bg = B + (size_t)(n0 + w * 16 + lr) * K + lc;

#pragma unroll
  for (int i = 0; i < 2; i++) gload_lds16(Ag[i], As + w * 1024 + i * 512);
  gload_lds16(Bg, Bs + w * 512);

  int cur = 0;
  for (int k0 = 0; k0 < K; k0 += 32) {
    asm volatile("s_waitcnt vmcnt(0)" ::: "memory");
    __builtin_amdgcn_s_barrier();
    __builtin_amdgcn_sched_barrier(0);
    if (k0 + 32 < K) {
      int nb = cur ^ 1;
#pragma unroll
      for (int i = 0; i < 2; i++)
        gload_lds16(Ag[i] + k0 + 32, As + nb * 4096 + w * 1024 + i * 512);
      gload_lds16(Bg + k0 + 32, Bs + nb * 2048 + w * 512);
    }
    __builtin_amdgcn_sched_barrier(0);
    const ush* Asc = As + cur * 4096;
    const ush* Bsc = Bs + cur * 2048;
    bf16x8 af[FI], bfr[FJ];
#pragma unroll
    for (int i = 0; i < FI; i++)
      af[i] = *(const bf16x8*)(Asc + (wm * 64 + i * 16 + lm) * 32 + lq * 8);
#pragma unroll
    for (int j = 0; j < FJ; j++)
      bfr[j] = *(const bf16x8*)(Bsc + (wn * 32 + j * 16 + lm) * 32 + lq * 8);
#pragma unroll
    for (int i = 0; i < FI; i++)
#pragma unroll
      for (int j = 0; j < FJ; j++)
        acc[i][j] = __builtin_amdgcn_mfma_f32_16x16x32_f16(af[i], bfr[j], acc[i][j], 0, 0, 0);
    cur ^= 1;
  }

#pragma unroll
  for (int i = 0; i < FI; i++)
#pragma unroll
    for (int j = 0; j < FJ; j++)
#pragma unroll
      for (int r = 0; r < 4; r++) {
        int mm = m0 + wm * 64 + i * 16 + lq * 4 + r;
        int nn = n0 + wn * 32 + j * 16 + lm;
        float v = acc[i][j][r];
        if (nn < 512)       cqh[(size_t)mm * 512 + nn] = f2h(v);
        else if (nn < 1024) ckvh[(size_t)mm * 512 + nn - 512] = f2h(v);
        else if (nn < 1088) krl[(size_t)mm * 64 + nn - 1024] = v;
      }
}

// ---------------- merged up GEMM (qup blocks [0,48), kvup [48,112)): BM=128,BN=64,K=512,
// single-barrier dbuf, fp16 out ----------------
__global__ __launch_bounds__(256) void gemm_up(
    const ush* __restrict__ cqh, const ush* __restrict__ wqh,
    const ush* __restrict__ ckvh, const ush* __restrict__ wkvuh,
    ush* __restrict__ qupf, ush* __restrict__ kvf) {
  constexpr int BM = 128, BN = 64, K = 512, FI = 4, FJ = 2;
  __shared__ __align__(16) ush As[2 * BM * 32];
  __shared__ __align__(16) ush Bs[2 * BN * 32];
  int bx = blockIdx.x;
  const ush* A; const ush* B; ush* C; int ldc;
  if (bx < 48) { A = cqh; B = wqh; C = qupf; ldc = 3072; }
  else { bx -= 48; A = ckvh; B = wkvuh; C = kvf; ldc = 4096; }
  const int t = threadIdx.x, l = t & 63, w = t >> 6;
  const int wm = w & 1, wn = w >> 1;
  const int m0 = blockIdx.y * BM, n0 = bx * BN;
  const int lm = l & 15, lq = l >> 4;
  const int lr = l >> 2, lc = (l & 3) * 8;

  f32x4 acc[FI][FJ];
  const f32x4 zero = {0.f, 0.f, 0.f, 0.f};
#pragma unroll
  for (int i = 0; i < FI; i++)
#pragma unroll
    for (int j = 0; j < FJ; j++) acc[i][j] = zero;

  const ush* Ag[2];
#pragma unroll
  for (int i = 0; i < 2; i++) Ag[i] = A + (size_t)(m0 + w * 32 + i * 16 + lr) * K + lc;
  const ush* Bg = B + (size_t)(n0 + w * 16 + lr) * K + lc;

#pragma unroll
  for (int i = 0; i < 2; i++) gload_lds16(Ag[i], As + w * 1024 + i * 512);
  gload_lds16(Bg, Bs + w * 512);

  int cur = 0;
  for (int k0 = 0; k0 < K; k0 += 32) {
    asm volatile("s_waitcnt vmcnt(0)" ::: "memory");
    __builtin_amdgcn_s_barrier();
    __builtin_amdgcn_sched_barrier(0);
    if (k0 + 32 < K) {
      int nb = cur ^ 1;
#pragma unroll
      for (int i = 0; i < 2; i++)
        gload_lds16(Ag[i] + k0 + 32, As + nb * 4096 + w * 1024 + i * 512);
      gload_lds16(Bg + k0 + 32, Bs + nb * 2048 + w * 512);
    }
    __builtin_amdgcn_sched_barrier(0);
    const ush* Asc = As + cur * 4096;
    const ush* Bsc = Bs + cur * 2048;
    bf16x8 af[FI], bfr[FJ];
#pragma unroll
    for (int i = 0; i < FI; i++)
      af[i] = *(const bf16x8*)(Asc + (wm * 64 + i * 16 + lm) * 32 + lq * 8);
#pragma unroll
    for (int j = 0; j < FJ; j++)
      bfr[j] = *(const bf16x8*)(Bsc + (wn * 32 + j * 16 + lm) * 32 + lq * 8);
#pragma unroll
    for (int i = 0; i < FI; i++)
#pragma unroll
      for (int j = 0; j < FJ; j++)
        acc[i][j] = __builtin_amdgcn_mfma_f32_16x16x32_f16(af[i], bfr[j], acc[i][j], 0, 0, 0);
    cur ^= 1;
  }

#pragma unroll
  for (int i = 0; i < FI; i++)
#pragma unroll
    for (int j = 0; j < FJ; j++)
#pragma unroll
      for (int r = 0; r < 4; r++) {
        int mm = m0 + wm * 64 + i * 16 + lq * 4 + r;
        int nn = n0 + wn * 32 + j * 16 + lm;
        C[(size_t)mm * ldc + nn] = f2h(acc[i][j][r]);
      }
}

// ---------------- out GEMM: BM=128,BN=64, single-barrier dbuf, f32 out ----------------
__global__ __launch_bounds__(256) void gemm_out(
    const ush* __restrict__ A, const ush* __restrict__ B, float* __restrict__ C,
    int K, int ldc) {
  constexpr int BM = 128, BN = 64, FI = 4, FJ = 2;
  __shared__ __align__(16) ush As[2 * BM * 32];
  __shared__ __align__(16) ush Bs[2 * BN * 32];
  const int t = threadIdx.x, l = t & 63, w = t >> 6;
  const int wm = w & 1, wn = w >> 1;
  const int m0 = blockIdx.y * BM, n0 = blockIdx.x * BN;
  const int lm = l & 15, lq = l >> 4;
  const int lr = l >> 2, lc = (l & 3) * 8;

  f32x4 acc[FI][FJ];
  const f32x4 zero = {0.f, 0.f, 0.f, 0.f};
#pragma unroll
  for (int i = 0; i < FI; i++)
#pragma unroll
    for (int j = 0; j < FJ; j++) acc[i][j] = zero;

  const ush* Ag[2];
#pragma unroll
  for (int i = 0; i < 2; i++) Ag[i] = A + (size_t)(m0 + w * 32 + i * 16 + lr) * K + lc;
  const ush* Bg = B + (size_t)(n0 + w * 16 + lr) * K + lc;

#pragma unroll
  for (int i = 0; i < 2; i++) gload_lds16(Ag[i], As + w * 1024 + i * 512);
  gload_lds16(Bg, Bs + w * 512);

  int cur = 0;
  for (int k0 = 0; k0 < K; k0 += 32) {
    asm volatile("s_waitcnt vmcnt(0)" ::: "memory");
    __builtin_amdgcn_s_barrier();
    __builtin_amdgcn_sched_barrier(0);
    if (k0 + 32 < K) {
      int nb = cur ^ 1;
#pragma unroll
      for (int i = 0; i < 2; i++)
        gload_lds16(Ag[i] + k0 + 32, As + nb * 4096 + w * 1024 + i * 512);
      gload_lds16(Bg + k0 + 32, Bs + nb * 2048 + w * 512);
    }
    __builtin_amdgcn_sched_barrier(0);
    const ush* Asc = As + cur * 4096;
    const ush* Bsc = Bs + cur * 2048;
    bf16x8 af[FI], bfr[FJ];
#pragma unroll
    for (int i = 0; i < FI; i++)
      af[i] = *(const bf16x8*)(Asc + (wm * 64 + i * 16 + lm) * 32 + lq * 8);
#pragma unroll
    for (int j = 0; j < FJ; j++)
      bfr[j] = *(const bf16x8*)(Bsc + (wn * 32 + j * 16 + lm) * 32 + lq * 8);
#pragma unroll
    for (int i = 0; i < FI; i++)
#pragma unroll
      for (int j = 0; j < FJ; j++)
        acc[i][j] = __builtin_amdgcn_mfma_f32_16x16x32_f16(af[i], bfr[j], acc[i][j], 0, 0, 0);
    cur ^= 1;
  }

#pragma unroll
  for (int i = 0; i < FI; i++)
#pragma unroll
    for (int j = 0; j < FJ; j++)
#pragma unroll
      for (int r = 0; r < 4; r++) {
        int mm = m0 + wm * 64 + i * 16 + lq * 4 + r;
        int nn = n0 + wn * 32 + j * 16 + lm;
        C[(size_t)mm * ldc + nn] = acc[i][j][r];
      }
}

// ---------------- builders: qb(scale-folded) + padded-tiled kbt + vtrans (merged) ----------------
__global__ void build_all(const ush* __restrict__ qupf, const ush* __restrict__ kvf,
                          const float* __restrict__ krl, const float* __restrict__ tab,
                          ush* __restrict__ qb, ush* __restrict__ kbt, ush* __restrict__ vtt) {
  const float scale = 0.07216878364870323f;  // 1/sqrt(192), folded into q
  if (blockIdx.x >= 50176) {  // vtrans: (s,d) fp16 -> (h,T,d[128],c[72]) bf16
    __shared__ ush Vt[128 * 72];
    int b = blockIdx.x - 50176;
    const int T = b & 31, h = b >> 5, t = threadIdx.x;
    const int key = t >> 5, d0 = (t & 31) * 4;
#pragma unroll
    for (int pass = 0; pass < 8; ++pass) {
      int k = key + pass * 8;
      int s = T * 64 + k;
      ushort4 v = *(const ushort4*)(kvf + (size_t)s * 4096 + 2048 + h * 128 + d0);
      Vt[(d0 + 0) * 72 + k] = f2bf(h2f(v.x));
      Vt[(d0 + 1) * 72 + k] = f2bf(h2f(v.y));
      Vt[(d0 + 2) * 72 + k] = f2bf(h2f(v.z));
      Vt[(d0 + 3) * 72 + k] = f2bf(h2f(v.w));
    }
    __syncthreads();
    ush* dst = vtt + (size_t)(h * 32 + T) * 9216;
    for (int off = t; off < 1152; off += 256) {
      int row = off / 9, c8 = (off % 9) * 8;
      *(bf16x8*)(dst + row * 72 + c8) = *(const bf16x8*)(Vt + row * 72 + c8);
    }
    return;
  }
  int idx = blockIdx.x * 256 + threadIdx.x;
  if (idx < 6291456) {  // qb (h,s,192), pre-scaled
    int d = idx % 192; int sh = idx / 192; int h = sh & 15; int s = sh >> 4;
    ush v;
    if (d < 128) {
      v = f2bf(h2f(qupf[(size_t)s * 3072 + h * 128 + d]) * scale);
    } else {
      int r = d - 128, i = r & 31;
      float sn = tab[s * 32 + i], cs = tab[65536 + s * 32 + i];
      const ush* qr = qupf + (size_t)s * 3072 + 2048 + h * 64;
      float xv = h2f(qr[r]);
      float other = (r < 32) ? -h2f(qr[r + 32]) : h2f(qr[r - 32]);
      v = f2bf((xv * cs + other * sn) * scale);
    }
    qb[((size_t)h * S_LEN + s) * 192 + d] = v;
    return;
  }
  idx -= 6291456;
  if (idx < 6553600) {  // kbt (h,T,key[64],c[200])
    int c = idx % 200; int r2 = idx / 200;
    int key = r2 & 63; int r3 = r2 >> 6; int T = r3 & 31; int h = r3 >> 5;
    int s = T * 64 + key;
    ush v = 0;
    if (c < 128) {
      v = f2bf(h2f(kvf[(size_t)s * 4096 + h * 128 + c]));
    } else if (c < 192) {
      int r = c - 128, i = r & 31;
      float sn = tab[s * 32 + i], cs = tab[65536 + s * 32 + i];
      const float* kr = krl + (size_t)s * 64;
      float xv = kr[r];
      float other = (r < 32) ? -kr[r + 32] : kr[r - 32];
      v = f2bf(xv * cs + other * sn);
    }
    kbt[((size_t)(h * 32 + T) * 64 + key) * 200 + c] = v;
  }
}

// ---------------- flash attention (exact R3 body): single barrier/iter, dbuf K+V,
// prefetch-after-barrier, QK0-SM0-QK1-PV0-SM1-PV1 interleave, __expf, permlane32_swap, z=2 ----------------
__global__ __launch_bounds__(512, 2) void attn_fused(
    const ush* __restrict__ qb, const ush* __restrict__ kbt, const ush* __restrict__ vtt,
    ush* __restrict__ opart, float* __restrict__ ml) {
  __shared__ __align__(16) ush Ks[2][64 * 200];   // 2 x 25.6 KB
  __shared__ __align__(16) ush Vs[2][128 * 72];   // 2 x 18.4 KB  (88 KB total)
  const int t = threadIdx.x, l = t & 63, w = t >> 6;   // 8 waves
  const int id = blockIdx.x + 8 * (blockIdx.y + 16 * blockIdx.z);
  const int wid = (id & 7) * 32 + (id >> 3);
  const int qx = wid & 7, h = (wid >> 3) & 15, z = wid >> 7;
  const int qrow0 = qx * 256 + w * 32;
  const int ln = l & 31, lh = l >> 5;

  bf16x8 qf[12];
#pragma unroll
  for (int st = 0; st < 12; st++)
    qf[st] = *(const bf16x8*)(qb + ((size_t)h * S_LEN + qrow0 + ln) * 192 + st * 16 + lh * 8);
#pragma unroll
  for (int st = 0; st < 12; st++) asm volatile("" : "+v"(qf[st]));

  f32x16 o[4];
#pragma unroll
  for (int i = 0; i < 4; i++)
#pragma unroll
    for (int r = 0; r < 16; r++) o[i][r] = 0.f;
  float ps = 0.f;  // per-lane sum of exp; partner lane (l^32) holds other half

  const ush* kbase = kbt + (size_t)(h * 32 + z * 16) * 12800;
  const ush* vbase = vtt + (size_t)(h * 32 + z * 16) * 9216;

  // softmax pack: sv (16 scores) -> exp -> bf16 pairs -> lane^32 half-exchange
  auto smpack = [&ps](const f32x16& svv, bf16x8& f0, bf16x8& f1) {
    unsigned pk8[8];
#pragma unroll
    for (int g = 0; g < 4; g++) {
      float p0 = __expf(svv[4 * g + 0]);   // scale pre-folded into q
      float p1 = __expf(svv[4 * g + 1]);
      float p2 = __expf(svv[4 * g + 2]);
      float p3 = __expf(svv[4 * g + 3]);
      ps += (p0 + p1) + (p2 + p3);
      unsigned lo, hi;
      asm("v_cvt_pk_bf16_f32 %0, %1, %2" : "=v"(lo) : "v"(p0), "v"(p1));
      asm("v_cvt_pk_bf16_f32 %0, %1, %2" : "=v"(hi) : "v"(p2), "v"(p3));
      pk8[2 * g] = lo; pk8[2 * g + 1] = hi;
    }
    asm("v_permlane32_swap_b32 %0, %1" : "+v"(pk8[0]), "+v"(pk8[2]));
    asm("v_permlane32_swap_b32 %0, %1" : "+v"(pk8[1]), "+v"(pk8[3]));
    asm("v_permlane32_swap_b32 %0, %1" : "+v"(pk8[4]), "+v"(pk8[6]));
    asm("v_permlane32_swap_b32 %0, %1" : "+v"(pk8[5]), "+v"(pk8[7]));
    union { unsigned d[4]; bf16x8 v; } u0, u1;
    u0.d[0] = pk8[0]; u0.d[1] = pk8[1]; u0.d[2] = pk8[2]; u0.d[3] = pk8[3];
    u1.d[0] = pk8[4]; u1.d[1] = pk8[5]; u1.d[2] = pk8[6]; u1.d[3] = pk8[7];
    f0 = u0.v; f1 = u1.v;
  };

  // prologue: stage tile 0 into buf 0 (43 chunks of 1 KB over 8 waves)
  for (int c = w; c < 43; c += 8) {
    if (c < 25) gload_lds16(kbase + c * 512 + l * 8, &Ks[0][c * 512]);
    else        gload_lds16(vbase + (c - 25) * 512 + l * 8, &Vs[0][(c - 25) * 512]);
  }

  int cur = 0;
  for (int it = 0; it < 16; ++it) {
    // drain own loads for tile it (issued a full iteration ago), then publish
    asm volatile("s_waitcnt vmcnt(0)" ::: "memory");
    __builtin_amdgcn_s_barrier();
    __builtin_amdgcn_sched_barrier(0);
    // issue next-tile prefetch AFTER the barrier; stays in flight under this iter's compute
    if (it < 15) {
      const ush* ksrc = kbase + (size_t)(it + 1) * 12800;
      const ush* vsrc = vbase + (size_t)(it + 1) * 9216;
      ush* kd = &Ks[cur ^ 1][0];
      ush* vd = &Vs[cur ^ 1][0];
      for (int c = w; c < 43; c += 8) {
        if (c < 25) gload_lds16(ksrc + c * 512 + l * 8, kd + c * 512);
        else        gload_lds16(vsrc + (c - 25) * 512 + l * 8, vd + (c - 25) * 512);
      }
    }
    __builtin_amdgcn_sched_barrier(0);

    const ush* Kb = &Ks[cur][0];
    const ush* Vb = &Vs[cur][0];

    f32x16 sv0, sv1;
#pragma unroll
    for (int r = 0; r < 16; r++) { sv0[r] = 0.f; sv1[r] = 0.f; }

    // QK kb0
    __builtin_amdgcn_s_setprio(1);
#pragma unroll
    for (int st = 0; st < 12; st++) {
      bf16x8 af = *(const bf16x8*)(Kb + ln * 200 + st * 16 + lh * 8);
      sv0 = __builtin_amdgcn_mfma_f32_32x32x16_bf16(af, qf[st], sv0, 0, 0, 0);
    }
    __builtin_amdgcn_s_setprio(0);

    // SM kb0 (VALU) — overlaps QK kb1 (MFMA)
    bf16x8 pf00, pf01;
    smpack(sv0, pf00, pf01);

    // QK kb1
    __builtin_amdgcn_s_setprio(1);
#pragma unroll
    for (int st = 0; st < 12; st++) {
      bf16x8 af = *(const bf16x8*)(Kb + (32 + ln) * 200 + st * 16 + lh * 8);
      sv1 = __builtin_amdgcn_mfma_f32_32x32x16_bf16(af, qf[st], sv1, 0, 0, 0);
    }
    __builtin_amdgcn_s_setprio(0);

    // PV kb0
    __builtin_amdgcn_s_setprio(1);
#pragma unroll
    for (int db = 0; db < 4; db++) {
      bf16x8 vf0 = *(const bf16x8*)(Vb + (db * 32 + ln) * 72 + lh * 8);
      bf16x8 vf1 = *(const bf16x8*)(Vb + (db * 32 + ln) * 72 + 16 + lh * 8);
      o[db] = __builtin_amdgcn_mfma_f32_32x32x16_bf16(vf0, pf00, o[db], 0, 0, 0);
      o[db] = __builtin_amdgcn_mfma_f32_32x32x16_bf16(vf1, pf01, o[db], 0, 0, 0);
    }
    __builtin_amdgcn_s_setprio(0);

    // SM kb1
    bf16x8 pf10, pf11;
    smpack(sv1, pf10, pf11);

    // PV kb1
    __builtin_amdgcn_s_setprio(1);
#pragma unroll
    for (int db = 0; db < 4; db++) {
      bf16x8 vf0 = *(const bf16x8*)(Vb + (db * 32 + ln) * 72 + 32 + lh * 8);
      bf16x8 vf1 = *(const bf16x8*)(Vb + (db * 32 + ln) * 72 + 48 + lh * 8);
      o[db] = __builtin_amdgcn_mfma_f32_32x32x16_bf16(vf0, pf10, o[db], 0, 0, 0);
      o[db] = __builtin_amdgcn_mfma_f32_32x32x16_bf16(vf1, pf11, o[db], 0, 0, 0);
    }
    __builtin_amdgcn_s_setprio(0);

    cur ^= 1;
  }

  float lsum = ps + __shfl_xor(ps, 32, 64);
  const int s = qrow0 + ln;
  const size_t rbase = ((size_t)((z * 16 + h) * 2048) + s) * 128;
#pragma unroll
  for (int db = 0; db < 4; db++)
#pragma unroll
    for (int rq = 0; rq < 4; rq++) {
      ushort4 v4;
      v4.x = f2h(o[db][rq * 4 + 0] * 0.0625f);   // /16 safety scale vs fp16 range
      v4.y = f2h(o[db][rq * 4 + 1] * 0.0625f);
      v4.z = f2h(o[db][rq * 4 + 2] * 0.0625f);
      v4.w = f2h(o[db][rq * 4 + 3] * 0.0625f);
      *(ushort4*)(&opart[rbase + db * 32 + 8 * rq + 4 * lh]) = v4;
    }
  if (lh == 0) ml[(size_t)(z * 16 + h) * 2048 + s] = lsum;
}

// ---------------- reduction: fp16 partials (x16 descale) -> fp16 attn (z=2) ----------------
__global__ __launch_bounds__(256) void attn_reduce(const ush* __restrict__ opart,
                                                   const float* __restrict__ ml,
                                                   ush* __restrict__ attnh) {
  int row = blockIdx.x * 4 + (threadIdx.x >> 6);
  int l = threadIdx.x & 63;
  int h = row >> 11, s = row & 2047;
  float lsum = 0.f;
#pragma unroll
  for (int z = 0; z < 2; z++) lsum += ml[(size_t)(z * 16 + h) * 2048 + s];
  float inv = 16.0f / lsum;
#pragma unroll
  for (int c0 = 0; c0 < 128; c0 += 64) {
    int c = c0 + l;
    float acc = 0.f;
#pragma unroll
    for (int z = 0; z < 2; z++)
      acc += h2f(opart[((size_t)(z * 16 + h) * 2048 + s) * 128 + c]);
    attnh[(size_t)s * 2048 + h * 128 + c] = f2h(bf2f(f2bf(acc * inv)));
  }
}

// ---------------- launch ----------------
extern "C" void kernel_launch(void* const* d_in, const int* in_sizes, int n_in,
                              void* d_out, int out_size, void* d_ws, size_t ws_size,
                              hipStream_t stream) {
  const float* x        = (const float*)d_in[0];
  const float* wq_down  = (const float*)d_in[1];
  const float* wq_up    = (const float*)d_in[2];
  const float* wq_rope  = (const float*)d_in[3];
  const float* wkv_down = (const float*)d_in[4];
  const float* wkv_up   = (const float*)d_in[5];
  const float* wk_rope  = (const float*)d_in[6];
  const float* wo       = (const float*)d_in[7];
  char* ws = (char*)d_ws;

  size_t off = 0;
  auto alloc = [&](size_t b) { size_t c = off; off += (b + 255) & ~(size_t)255; return c; };
  const size_t XH    = alloc(2048UL * 2048 * 2);      // x fp16 (aliased by ATTNH later)
  const size_t WDH   = alloc(1152UL * 2048 * 2);
  const size_t KRL   = alloc(2048UL * 64 * 4);
  const size_t CQH   = alloc(2048UL * 512 * 2);
  const size_t CKVH  = alloc(2048UL * 512 * 2);
  const size_t WQH   = alloc(3072UL * 512 * 2);
  const size_t QUPF  = alloc(2048UL * 3072 * 2);
  const size_t WKVUH = alloc(4096UL * 512 * 2);
  const size_t WOH   = alloc(2048UL * 2048 * 2);
  const size_t KVF   = alloc(2048UL * 4096 * 2);
  const size_t QB    = alloc(16UL * 2048 * 192 * 2);
  const size_t KBT   = alloc(16UL * 32 * 12800 * 2);
  const size_t VTT   = alloc(16UL * 32 * 9216 * 2);
  const size_t TAB   = alloc(2048UL * 32 * 4 * 2);
  const size_t OPART = alloc(2UL * 16 * 2048 * 128 * 2);  // fp16 partials (z=2)
  const size_t ML    = alloc(2UL * 16 * 2048 * 4);
  const size_t ATTNH = XH;  // x fp16 dead after down-proj

  // mega pack: 3604480 quad-threads + 65536 rope = 3670016 threads = 14336 blocks
  mega_pack<<<dim3(14336), 256, 0, stream>>>(
      wq_down, wkv_down, wk_rope, wq_up, wq_rope, wkv_up, wo, x,
      (ush*)(ws + WDH), (ush*)(ws + WQH), (ush*)(ws + WKVUH),
      (ush*)(ws + WOH), (ush*)(ws + XH), (float*)(ws + TAB));

  // down: (2048x2048)*(1152x2048)^T -> fp16 cq/ckv + f32 krl, 128x64 tiles
  gemm_down<<<dim3(18, 16), 256, 0, stream>>>(
      (ush*)(ws + XH), (ush*)(ws + WDH),
      (ush*)(ws + CQH), (ush*)(ws + CKVH), (float*)(ws + KRL));

  // merged q-up + kv-up (one launch, 1792 blocks)
  gemm_up<<<dim3(112, 16), 256, 0, stream>>>(
      (ush*)(ws + CQH), (ush*)(ws + WQH),
      (ush*)(ws + CKVH), (ush*)(ws + WKVUH),
      (ush*)(ws + QUPF), (ush*)(ws + KVF));

  // builders + vtrans merged
  build_all<<<dim3(50688), 256, 0, stream>>>(
      (const ush*)(ws + QUPF), (const ush*)(ws + KVF), (const float*)(ws + KRL),
      (const float*)(ws + TAB), (ush*)(ws + QB), (ush*)(ws + KBT), (ush*)(ws + VTT));

  // attn: 256 blocks (8 qx x 16 h x z=2), 512 threads
  attn_fused<<<dim3(8, 16, 2), 512, 0, stream>>>(
      (ush*)(ws + QB), (ush*)(ws + KBT), (ush*)(ws + VTT),
      (ush*)(ws + OPART), (float*)(ws + ML));
  attn_reduce<<<dim3(8192), 256, 0, stream>>>((const ush*)(ws + OPART), (const float*)(ws + ML),
                                              (ush*)(ws + ATTNH));

  // out: (2048x2048)*(2048x2048)^T -> d_out f32
  gemm_out<<<dim3(32, 16), 256, 0, stream>>>(
      (ush*)(ws + ATTNH), (ush*)(ws + WOH), (float*)d_out, 2048, 2048);
}

// Round 12
// 276.777 us; speedup vs baseline: 1.1596x; 1.0821x over previous
//
#include <hip/hip_runtime.h>
#include <stdint.h>
#include <math.h>

#define S_LEN 2048
#define NH 16

typedef __attribute__((ext_vector_type(8))) short bf16x8;
typedef __attribute__((ext_vector_type(4))) float f32x4;
typedef __attribute__((ext_vector_type(16))) float f32x16;
typedef unsigned short ush;

__device__ __forceinline__ ush f2bf(float f) {   // RNE float->bf16
  union { float f; unsigned u; } v; v.f = f;
  unsigned x = v.u;
  return (ush)((x + 0x7fffu + ((x >> 16) & 1u)) >> 16);
}
__device__ __forceinline__ float bf2f(ush b) {
  union { unsigned u; float f; } v; v.u = ((unsigned)b) << 16;
  return v.f;
}
__device__ __forceinline__ ush f2h(float f) {    // RNE float->fp16
  _Float16 h = (_Float16)f;
  union { _Float16 h; ush u; } v; v.h = h;
  return v.u;
}
__device__ __forceinline__ float h2f(ush u) {
  union { ush u; _Float16 h; } v; v.u = u;
  return (float)v.h;
}

// async global->LDS, 16B/lane; LDS dest = wave-uniform base + lane*16
__device__ __forceinline__ void gload_lds16(const ush* g, ush* l) {
  __builtin_amdgcn_global_load_lds((const __attribute__((address_space(1))) void*)g,
                                   (__attribute__((address_space(3))) void*)l, 16, 0, 0);
}

// ---------------- mega pack v2: float4-vectorized (4 elem/thread), ONE launch ----------------
__global__ void mega_pack(const float* __restrict__ wq_down, const float* __restrict__ wkv_down,
                          const float* __restrict__ wk_rope, const float* __restrict__ wq_up,
                          const float* __restrict__ wq_rope, const float* __restrict__ wkv_up,
                          const float* __restrict__ wo, const float* __restrict__ x,
                          ush* __restrict__ wdh, ush* __restrict__ wqh, ush* __restrict__ wkvuh,
                          ush* __restrict__ woh, ush* __restrict__ xh, float* __restrict__ tab) {
  int idx = blockIdx.x * 256 + threadIdx.x;
  if (idx < 3604480) {        // quad-converters: 14417920 f32 elements / 4
    int qi = idx * 4;
    if (qi < 2359296) {       // fused down weights [wq_down|wkv_down|wk_rope|0] 1152x2048
      int r = qi >> 11, c = qi & 2047;
      float4 v = {0.f, 0.f, 0.f, 0.f};
      if (r < 512)       v = *(const float4*)(wq_down + (size_t)r * 2048 + c);
      else if (r < 1024) v = *(const float4*)(wkv_down + (size_t)(r - 512) * 2048 + c);
      else if (r < 1088) v = *(const float4*)(wk_rope + (size_t)(r - 1024) * 2048 + c);
      ushort4 o4; o4.x = f2h(v.x); o4.y = f2h(v.y); o4.z = f2h(v.z); o4.w = f2h(v.w);
      *(ushort4*)(wdh + qi) = o4;
      return;
    }
    qi -= 2359296;
    if (qi < 1572864) {       // fused [wq_up|wq_rope] 3072x512
      int r = qi >> 9, c = qi & 511;
      const float* src = (r < 2048) ? wq_up + (size_t)r * 512 + c
                                    : wq_rope + (size_t)(r - 2048) * 512 + c;
      float4 v = *(const float4*)src;
      ushort4 o4; o4.x = f2h(v.x); o4.y = f2h(v.y); o4.z = f2h(v.z); o4.w = f2h(v.w);
      *(ushort4*)(wqh + qi) = o4;
      return;
    }
    qi -= 1572864;
    if (qi < 2097152) {       // wkv_up 4096x512
      float4 v = *(const float4*)(wkv_up + qi);
      ushort4 o4; o4.x = f2h(v.x); o4.y = f2h(v.y); o4.z = f2h(v.z); o4.w = f2h(v.w);
      *(ushort4*)(wkvuh + qi) = o4;
      return;
    }
    qi -= 2097152;
    if (qi < 4194304) {       // wo 2048x2048
      float4 v = *(const float4*)(wo + qi);
      ushort4 o4; o4.x = f2h(v.x); o4.y = f2h(v.y); o4.z = f2h(v.z); o4.w = f2h(v.w);
      *(ushort4*)(woh + qi) = o4;
      return;
    }
    qi -= 4194304;
    {                         // x 2048x2048
      float4 v = *(const float4*)(x + qi);
      ushort4 o4; o4.x = f2h(v.x); o4.y = f2h(v.y); o4.z = f2h(v.z); o4.w = f2h(v.w);
      *(ushort4*)(xh + qi) = o4;
      return;
    }
  }
  idx -= 3604480;
  if (idx < 65536) {  // rope table
    int tt = idx >> 5, i = idx & 31;
    float inv_freq = 1.0f / powf(10000.0f, (float)i * (1.0f / 32.0f));
    float fr = (float)tt * inv_freq;
    tab[idx] = sinf(fr);
    tab[65536 + idx] = cosf(fr);
  }
}

// ---------------- down GEMM v2: BM=128,BN=64,K=2048, single-barrier dbuf, fused epilogue ----------------
__global__ __launch_bounds__(256) void gemm_down(
    const ush* __restrict__ A, const ush* __restrict__ B,
    ush* __restrict__ cqh, ush* __restrict__ ckvh, float* __restrict__ krl) {
  constexpr int BM = 128, BN = 64, K = 2048, FI = 4, FJ = 2;
  __shared__ __align__(16) ush As[2 * BM * 32];
  __shared__ __align__(16) ush Bs[2 * BN * 32];
  const int t = threadIdx.x, l = t & 63, w = t >> 6;
  const int wm = w & 1, wn = w >> 1;
  const int m0 = blockIdx.y * BM, n0 = blockIdx.x * BN;
  const int lm = l & 15, lq = l >> 4;
  const int lr = l >> 2, lc = (l & 3) * 8;

  f32x4 acc[FI][FJ];
  const f32x4 zero = {0.f, 0.f, 0.f, 0.f};
#pragma unroll
  for (int i = 0; i < FI; i++)
#pragma unroll
    for (int j = 0; j < FJ; j++) acc[i][j] = zero;

  const ush* Ag[2];
#pragma unroll
  for (int i = 0; i < 2; i++) Ag[i] = A + (size_t)(m0 + w * 32 + i * 16 + lr) * K + lc;
  const ush* Bg = B + (size_t)(n0 + w * 16 + lr) * K + lc;

#pragma unroll
  for (int i = 0; i < 2; i++) gload_lds16(Ag[i], As + w * 1024 + i * 512);
  gload_lds16(Bg, Bs + w * 512);

  int cur = 0;
  for (int k0 = 0; k0 < K; k0 += 32) {
    asm volatile("s_waitcnt vmcnt(0)" ::: "memory");
    __builtin_amdgcn_s_barrier();
    __builtin_amdgcn_sched_barrier(0);
    if (k0 + 32 < K) {
      int nb = cur ^ 1;
#pragma unroll
      for (int i = 0; i < 2; i++)
        gload_lds16(Ag[i] + k0 + 32, As + nb * 4096 + w * 1024 + i * 512);
      gload_lds16(Bg + k0 + 32, Bs + nb * 2048 + w * 512);
    }
    __builtin_amdgcn_sched_barrier(0);
    const ush* Asc = As + cur * 4096;
    const ush* Bsc = Bs + cur * 2048;
    bf16x8 af[FI], bfr[FJ];
#pragma unroll
    for (int i = 0; i < FI; i++)
      af[i] = *(const bf16x8*)(Asc + (wm * 64 + i * 16 + lm) * 32 + lq * 8);
#pragma unroll
    for (int j = 0; j < FJ; j++)
      bfr[j] = *(const bf16x8*)(Bsc + (wn * 32 + j * 16 + lm) * 32 + lq * 8);
#pragma unroll
    for (int i = 0; i < FI; i++)
#pragma unroll
      for (int j = 0; j < FJ; j++)
        acc[i][j] = __builtin_amdgcn_mfma_f32_16x16x32_f16(af[i], bfr[j], acc[i][j], 0, 0, 0);
    cur ^= 1;
  }

#pragma unroll
  for (int i = 0; i < FI; i++)
#pragma unroll
    for (int j = 0; j < FJ; j++)
#pragma unroll
      for (int r = 0; r < 4; r++) {
        int mm = m0 + wm * 64 + i * 16 + lq * 4 + r;
        int nn = n0 + wn * 32 + j * 16 + lm;
        float v = acc[i][j][r];
        if (nn < 512)       cqh[(size_t)mm * 512 + nn] = f2h(v);
        else if (nn < 1024) ckvh[(size_t)mm * 512 + nn - 512] = f2h(v);
        else if (nn < 1088) krl[(size_t)mm * 64 + nn - 1024] = v;
      }
}

// ---------------- merged up GEMM (qup blocks [0,48), kvup [48,112)): BM=128,BN=64,K=512,
// single-barrier dbuf, fp16 out ----------------
__global__ __launch_bounds__(256) void gemm_up(
    const ush* __restrict__ cqh, const ush* __restrict__ wqh,
    const ush* __restrict__ ckvh, const ush* __restrict__ wkvuh,
    ush* __restrict__ qupf, ush* __restrict__ kvf) {
  constexpr int BM = 128, BN = 64, K = 512, FI = 4, FJ = 2;
  __shared__ __align__(16) ush As[2 * BM * 32];
  __shared__ __align__(16) ush Bs[2 * BN * 32];
  int bx = blockIdx.x;
  const ush* A; const ush* B; ush* C; int ldc;
  if (bx < 48) { A = cqh; B = wqh; C = qupf; ldc = 3072; }
  else { bx -= 48; A = ckvh; B = wkvuh; C = kvf; ldc = 4096; }
  const int t = threadIdx.x, l = t & 63, w = t >> 6;
  const int wm = w & 1, wn = w >> 1;
  const int m0 = blockIdx.y * BM, n0 = bx * BN;
  const int lm = l & 15, lq = l >> 4;
  const int lr = l >> 2, lc = (l & 3) * 8;

  f32x4 acc[FI][FJ];
  const f32x4 zero = {0.f, 0.f, 0.f, 0.f};
#pragma unroll
  for (int i = 0; i < FI; i++)
#pragma unroll
    for (int j = 0; j < FJ; j++) acc[i][j] = zero;

  const ush* Ag[2];
#pragma unroll
  for (int i = 0; i < 2; i++) Ag[i] = A + (size_t)(m0 + w * 32 + i * 16 + lr) * K + lc;
  const ush* Bg = B + (size_t)(n0 + w * 16 + lr) * K + lc;

#pragma unroll
  for (int i = 0; i < 2; i++) gload_lds16(Ag[i], As + w * 1024 + i * 512);
  gload_lds16(Bg, Bs + w * 512);

  int cur = 0;
  for (int k0 = 0; k0 < K; k0 += 32) {
    asm volatile("s_waitcnt vmcnt(0)" ::: "memory");
    __builtin_amdgcn_s_barrier();
    __builtin_amdgcn_sched_barrier(0);
    if (k0 + 32 < K) {
      int nb = cur ^ 1;
#pragma unroll
      for (int i = 0; i < 2; i++)
        gload_lds16(Ag[i] + k0 + 32, As + nb * 4096 + w * 1024 + i * 512);
      gload_lds16(Bg + k0 + 32, Bs + nb * 2048 + w * 512);
    }
    __builtin_amdgcn_sched_barrier(0);
    const ush* Asc = As + cur * 4096;
    const ush* Bsc = Bs + cur * 2048;
    bf16x8 af[FI], bfr[FJ];
#pragma unroll
    for (int i = 0; i < FI; i++)
      af[i] = *(const bf16x8*)(Asc + (wm * 64 + i * 16 + lm) * 32 + lq * 8);
#pragma unroll
    for (int j = 0; j < FJ; j++)
      bfr[j] = *(const bf16x8*)(Bsc + (wn * 32 + j * 16 + lm) * 32 + lq * 8);
#pragma unroll
    for (int i = 0; i < FI; i++)
#pragma unroll
      for (int j = 0; j < FJ; j++)
        acc[i][j] = __builtin_amdgcn_mfma_f32_16x16x32_f16(af[i], bfr[j], acc[i][j], 0, 0, 0);
    cur ^= 1;
  }

#pragma unroll
  for (int i = 0; i < FI; i++)
#pragma unroll
    for (int j = 0; j < FJ; j++)
#pragma unroll
      for (int r = 0; r < 4; r++) {
        int mm = m0 + wm * 64 + i * 16 + lq * 4 + r;
        int nn = n0 + wn * 32 + j * 16 + lm;
        C[(size_t)mm * ldc + nn] = f2h(acc[i][j][r]);
      }
}

// ---------------- out GEMM: BM=128,BN=64, single-barrier dbuf, f32 out ----------------
__global__ __launch_bounds__(256) void gemm_out(
    const ush* __restrict__ A, const ush* __restrict__ B, float* __restrict__ C,
    int K, int ldc) {
  constexpr int BM = 128, BN = 64, FI = 4, FJ = 2;
  __shared__ __align__(16) ush As[2 * BM * 32];
  __shared__ __align__(16) ush Bs[2 * BN * 32];
  const int t = threadIdx.x, l = t & 63, w = t >> 6;
  const int wm = w & 1, wn = w >> 1;
  const int m0 = blockIdx.y * BM, n0 = blockIdx.x * BN;
  const int lm = l & 15, lq = l >> 4;
  const int lr = l >> 2, lc = (l & 3) * 8;

  f32x4 acc[FI][FJ];
  const f32x4 zero = {0.f, 0.f, 0.f, 0.f};
#pragma unroll
  for (int i = 0; i < FI; i++)
#pragma unroll
    for (int j = 0; j < FJ; j++) acc[i][j] = zero;

  const ush* Ag[2];
#pragma unroll
  for (int i = 0; i < 2; i++) Ag[i] = A + (size_t)(m0 + w * 32 + i * 16 + lr) * K + lc;
  const ush* Bg = B + (size_t)(n0 + w * 16 + lr) * K + lc;

#pragma unroll
  for (int i = 0; i < 2; i++) gload_lds16(Ag[i], As + w * 1024 + i * 512);
  gload_lds16(Bg, Bs + w * 512);

  int cur = 0;
  for (int k0 = 0; k0 < K; k0 += 32) {
    asm volatile("s_waitcnt vmcnt(0)" ::: "memory");
    __builtin_amdgcn_s_barrier();
    __builtin_amdgcn_sched_barrier(0);
    if (k0 + 32 < K) {
      int nb = cur ^ 1;
#pragma unroll
      for (int i = 0; i < 2; i++)
        gload_lds16(Ag[i] + k0 + 32, As + nb * 4096 + w * 1024 + i * 512);
      gload_lds16(Bg + k0 + 32, Bs + nb * 2048 + w * 512);
    }
    __builtin_amdgcn_sched_barrier(0);
    const ush* Asc = As + cur * 4096;
    const ush* Bsc = Bs + cur * 2048;
    bf16x8 af[FI], bfr[FJ];
#pragma unroll
    for (int i = 0; i < FI; i++)
      af[i] = *(const bf16x8*)(Asc + (wm * 64 + i * 16 + lm) * 32 + lq * 8);
#pragma unroll
    for (int j = 0; j < FJ; j++)
      bfr[j] = *(const bf16x8*)(Bsc + (wn * 32 + j * 16 + lm) * 32 + lq * 8);
#pragma unroll
    for (int i = 0; i < FI; i++)
#pragma unroll
      for (int j = 0; j < FJ; j++)
        acc[i][j] = __builtin_amdgcn_mfma_f32_16x16x32_f16(af[i], bfr[j], acc[i][j], 0, 0, 0);
    cur ^= 1;
  }

#pragma unroll
  for (int i = 0; i < FI; i++)
#pragma unroll
    for (int j = 0; j < FJ; j++)
#pragma unroll
      for (int r = 0; r < 4; r++) {
        int mm = m0 + wm * 64 + i * 16 + lq * 4 + r;
        int nn = n0 + wn * 32 + j * 16 + lm;
        C[(size_t)mm * ldc + nn] = acc[i][j][r];
      }
}

// ---------------- builders v2: 8-wide vectorized qb + kbt, vtrans unchanged ----------------
__global__ void build_all(const ush* __restrict__ qupf, const ush* __restrict__ kvf,
                          const float* __restrict__ krl, const float* __restrict__ tab,
                          ush* __restrict__ qb, ush* __restrict__ kbt, ush* __restrict__ vtt) {
  const float scale = 0.07216878364870323f;  // 1/sqrt(192), folded into q
  if (blockIdx.x >= 6272) {  // vtrans: (s,d) fp16 -> (h,T,d[128],c[72]) bf16
    __shared__ ush Vt[128 * 72];
    int b = blockIdx.x - 6272;
    const int T = b & 31, h = b >> 5, t = threadIdx.x;
    const int key = t >> 5, d0 = (t & 31) * 4;
#pragma unroll
    for (int pass = 0; pass < 8; ++pass) {
      int k = key + pass * 8;
      int s = T * 64 + k;
      ushort4 v = *(const ushort4*)(kvf + (size_t)s * 4096 + 2048 + h * 128 + d0);
      Vt[(d0 + 0) * 72 + k] = f2bf(h2f(v.x));
      Vt[(d0 + 1) * 72 + k] = f2bf(h2f(v.y));
      Vt[(d0 + 2) * 72 + k] = f2bf(h2f(v.z));
      Vt[(d0 + 3) * 72 + k] = f2bf(h2f(v.w));
    }
    __syncthreads();
    ush* dst = vtt + (size_t)(h * 32 + T) * 9216;
    for (int off = t; off < 1152; off += 256) {
      int row = off / 9, c8 = (off % 9) * 8;
      *(bf16x8*)(dst + row * 72 + c8) = *(const bf16x8*)(Vt + row * 72 + c8);
    }
    return;
  }
  int idx = blockIdx.x * 256 + threadIdx.x;
  if (idx < 786432) {  // qb (h,s,192) 8-wide: 24 groups per (h,s)
    int g = idx % 24; int sh = idx / 24; int h = sh & 15; int s = sh >> 4;
    int d0 = g * 8;
    union { ush u[8]; bf16x8 v; } out;
    if (d0 < 128) {
      bf16x8 src = *(const bf16x8*)(qupf + (size_t)s * 3072 + h * 128 + d0);
#pragma unroll
      for (int e = 0; e < 8; e++) out.u[e] = f2bf(h2f((ush)src[e]) * scale);
    } else {
      int r = d0 - 128;           // multiple of 8; whole group in one rope half
      int i0 = r & 31;
      const ush* qr = qupf + (size_t)s * 3072 + 2048 + h * 64;
      bf16x8 xv = *(const bf16x8*)(qr + r);
      bf16x8 ov = (r < 32) ? *(const bf16x8*)(qr + r + 32) : *(const bf16x8*)(qr + r - 32);
      float4 sn0 = *(const float4*)(tab + s * 32 + i0);
      float4 sn1 = *(const float4*)(tab + s * 32 + i0 + 4);
      float4 cs0 = *(const float4*)(tab + 65536 + s * 32 + i0);
      float4 cs1 = *(const float4*)(tab + 65536 + s * 32 + i0 + 4);
      float sn[8] = {sn0.x, sn0.y, sn0.z, sn0.w, sn1.x, sn1.y, sn1.z, sn1.w};
      float cs[8] = {cs0.x, cs0.y, cs0.z, cs0.w, cs1.x, cs1.y, cs1.z, cs1.w};
#pragma unroll
      for (int e = 0; e < 8; e++) {
        float x = h2f((ush)xv[e]);
        float other = (r < 32) ? -h2f((ush)ov[e]) : h2f((ush)ov[e]);
        out.u[e] = f2bf((x * cs[e] + other * sn[e]) * scale);
      }
    }
    *(bf16x8*)(qb + ((size_t)h * S_LEN + s) * 192 + d0) = out.v;
    return;
  }
  idx -= 786432;
  {  // kbt (h,T,key[64],c[200]) 8-wide: 25 groups per row
    int g = idx % 25; int row = idx / 25;
    int key = row & 63; int r3 = row >> 6; int T = r3 & 31; int h = r3 >> 5;
    int s = T * 64 + key;
    int c0 = g * 8;
    union { ush u[8]; bf16x8 v; } out;
    if (c0 < 128) {
      bf16x8 src = *(const bf16x8*)(kvf + (size_t)s * 4096 + h * 128 + c0);
#pragma unroll
      for (int e = 0; e < 8; e++) out.u[e] = f2bf(h2f((ush)src[e]));
    } else if (c0 < 192) {
      int r = c0 - 128;           // multiple of 8; whole group in one rope half
      int i0 = r & 31;
      const float* kr = krl + (size_t)s * 64;
      float4 xv0 = *(const float4*)(kr + r);
      float4 xv1 = *(const float4*)(kr + r + 4);
      const float* kro = (r < 32) ? kr + r + 32 : kr + r - 32;
      float4 ov0 = *(const float4*)(kro);
      float4 ov1 = *(const float4*)(kro + 4);
      float4 sn0 = *(const float4*)(tab + s * 32 + i0);
      float4 sn1 = *(const float4*)(tab + s * 32 + i0 + 4);
      float4 cs0 = *(const float4*)(tab + 65536 + s * 32 + i0);
      float4 cs1 = *(const float4*)(tab + 65536 + s * 32 + i0 + 4);
      float xv[8] = {xv0.x, xv0.y, xv0.z, xv0.w, xv1.x, xv1.y, xv1.z, xv1.w};
      float ov[8] = {ov0.x, ov0.y, ov0.z, ov0.w, ov1.x, ov1.y, ov1.z, ov1.w};
      float sn[8] = {sn0.x, sn0.y, sn0.z, sn0.w, sn1.x, sn1.y, sn1.z, sn1.w};
      float cs[8] = {cs0.x, cs0.y, cs0.z, cs0.w, cs1.x, cs1.y, cs1.z, cs1.w};
#pragma unroll
      for (int e = 0; e < 8; e++) {
        float other = (r < 32) ? -ov[e] : ov[e];
        out.u[e] = f2bf(xv[e] * cs[e] + other * sn[e]);
      }
    } else {
#pragma unroll
      for (int e = 0; e < 8; e++) out.u[e] = 0;
    }
    *(bf16x8*)(kbt + ((size_t)(h * 32 + T) * 64 + key) * 200 + c0) = out.v;
  }
}

// ---------------- flash attention (exact R3 body): single barrier/iter, dbuf K+V,
// prefetch-after-barrier, QK0-SM0-QK1-PV0-SM1-PV1 interleave, __expf, permlane32_swap, z=2 ----------------
__global__ __launch_bounds__(512, 2) void attn_fused(
    const ush* __restrict__ qb, const ush* __restrict__ kbt, const ush* __restrict__ vtt,
    ush* __restrict__ opart, float* __restrict__ ml) {
  __shared__ __align__(16) ush Ks[2][64 * 200];   // 2 x 25.6 KB
  __shared__ __align__(16) ush Vs[2][128 * 72];   // 2 x 18.4 KB  (88 KB total)
  const int t = threadIdx.x, l = t & 63, w = t >> 6;   // 8 waves
  const int id = blockIdx.x + 8 * (blockIdx.y + 16 * blockIdx.z);
  const int wid = (id & 7) * 32 + (id >> 3);
  const int qx = wid & 7, h = (wid >> 3) & 15, z = wid >> 7;
  const int qrow0 = qx * 256 + w * 32;
  const int ln = l & 31, lh = l >> 5;

  bf16x8 qf[12];
#pragma unroll
  for (int st = 0; st < 12; st++)
    qf[st] = *(const bf16x8*)(qb + ((size_t)h * S_LEN + qrow0 + ln) * 192 + st * 16 + lh * 8);
#pragma unroll
  for (int st = 0; st < 12; st++) asm volatile("" : "+v"(qf[st]));

  f32x16 o[4];
#pragma unroll
  for (int i = 0; i < 4; i++)
#pragma unroll
    for (int r = 0; r < 16; r++) o[i][r] = 0.f;
  float ps = 0.f;  // per-lane sum of exp; partner lane (l^32) holds other half

  const ush* kbase = kbt + (size_t)(h * 32 + z * 16) * 12800;
  const ush* vbase = vtt + (size_t)(h * 32 + z * 16) * 9216;

  // softmax pack: sv (16 scores) -> exp -> bf16 pairs -> lane^32 half-exchange
  auto smpack = [&ps](const f32x16& svv, bf16x8& f0, bf16x8& f1) {
    unsigned pk8[8];
#pragma unroll
    for (int g = 0; g < 4; g++) {
      float p0 = __expf(svv[4 * g + 0]);   // scale pre-folded into q
      float p1 = __expf(svv[4 * g + 1]);
      float p2 = __expf(svv[4 * g + 2]);
      float p3 = __expf(svv[4 * g + 3]);
      ps += (p0 + p1) + (p2 + p3);
      unsigned lo, hi;
      asm("v_cvt_pk_bf16_f32 %0, %1, %2" : "=v"(lo) : "v"(p0), "v"(p1));
      asm("v_cvt_pk_bf16_f32 %0, %1, %2" : "=v"(hi) : "v"(p2), "v"(p3));
      pk8[2 * g] = lo; pk8[2 * g + 1] = hi;
    }
    asm("v_permlane32_swap_b32 %0, %1" : "+v"(pk8[0]), "+v"(pk8[2]));
    asm("v_permlane32_swap_b32 %0, %1" : "+v"(pk8[1]), "+v"(pk8[3]));
    asm("v_permlane32_swap_b32 %0, %1" : "+v"(pk8[4]), "+v"(pk8[6]));
    asm("v_permlane32_swap_b32 %0, %1" : "+v"(pk8[5]), "+v"(pk8[7]));
    union { unsigned d[4]; bf16x8 v; } u0, u1;
    u0.d[0] = pk8[0]; u0.d[1] = pk8[1]; u0.d[2] = pk8[2]; u0.d[3] = pk8[3];
    u1.d[0] = pk8[4]; u1.d[1] = pk8[5]; u1.d[2] = pk8[6]; u1.d[3] = pk8[7];
    f0 = u0.v; f1 = u1.v;
  };

  // prologue: stage tile 0 into buf 0 (43 chunks of 1 KB over 8 waves)
  for (int c = w; c < 43; c += 8) {
    if (c < 25) gload_lds16(kbase + c * 512 + l * 8, &Ks[0][c * 512]);
    else        gload_lds16(vbase + (c - 25) * 512 + l * 8, &Vs[0][(c - 25) * 512]);
  }

  int cur = 0;
  for (int it = 0; it < 16; ++it) {
    // drain own loads for tile it (issued a full iteration ago), then publish
    asm volatile("s_waitcnt vmcnt(0)" ::: "memory");
    __builtin_amdgcn_s_barrier();
    __builtin_amdgcn_sched_barrier(0);
    // issue next-tile prefetch AFTER the barrier; stays in flight under this iter's compute
    if (it < 15) {
      const ush* ksrc = kbase + (size_t)(it + 1) * 12800;
      const ush* vsrc = vbase + (size_t)(it + 1) * 9216;
      ush* kd = &Ks[cur ^ 1][0];
      ush* vd = &Vs[cur ^ 1][0];
      for (int c = w; c < 43; c += 8) {
        if (c < 25) gload_lds16(ksrc + c * 512 + l * 8, kd + c * 512);
        else        gload_lds16(vsrc + (c - 25) * 512 + l * 8, vd + (c - 25) * 512);
      }
    }
    __builtin_amdgcn_sched_barrier(0);

    const ush* Kb = &Ks[cur][0];
    const ush* Vb = &Vs[cur][0];

    f32x16 sv0, sv1;
#pragma unroll
    for (int r = 0; r < 16; r++) { sv0[r] = 0.f; sv1[r] = 0.f; }

    // QK kb0
    __builtin_amdgcn_s_setprio(1);
#pragma unroll
    for (int st = 0; st < 12; st++) {
      bf16x8 af = *(const bf16x8*)(Kb + ln * 200 + st * 16 + lh * 8);
      sv0 = __builtin_amdgcn_mfma_f32_32x32x16_bf16(af, qf[st], sv0, 0, 0, 0);
    }
    __builtin_amdgcn_s_setprio(0);

    // SM kb0 (VALU) — overlaps QK kb1 (MFMA)
    bf16x8 pf00, pf01;
    smpack(sv0, pf00, pf01);

    // QK kb1
    __builtin_amdgcn_s_setprio(1);
#pragma unroll
    for (int st = 0; st < 12; st++) {
      bf16x8 af = *(const bf16x8*)(Kb + (32 + ln) * 200 + st * 16 + lh * 8);
      sv1 = __builtin_amdgcn_mfma_f32_32x32x16_bf16(af, qf[st], sv1, 0, 0, 0);
    }
    __builtin_amdgcn_s_setprio(0);

    // PV kb0
    __builtin_amdgcn_s_setprio(1);
#pragma unroll
    for (int db = 0; db < 4; db++) {
      bf16x8 vf0 = *(const bf16x8*)(Vb + (db * 32 + ln) * 72 + lh * 8);
      bf16x8 vf1 = *(const bf16x8*)(Vb + (db * 32 + ln) * 72 + 16 + lh * 8);
      o[db] = __builtin_amdgcn_mfma_f32_32x32x16_bf16(vf0, pf00, o[db], 0, 0, 0);
      o[db] = __builtin_amdgcn_mfma_f32_32x32x16_bf16(vf1, pf01, o[db], 0, 0, 0);
    }
    __builtin_amdgcn_s_setprio(0);

    // SM kb1
    bf16x8 pf10, pf11;
    smpack(sv1, pf10, pf11);

    // PV kb1
    __builtin_amdgcn_s_setprio(1);
#pragma unroll
    for (int db = 0; db < 4; db++) {
      bf16x8 vf0 = *(const bf16x8*)(Vb + (db * 32 + ln) * 72 + 32 + lh * 8);
      bf16x8 vf1 = *(const bf16x8*)(Vb + (db * 32 + ln) * 72 + 48 + lh * 8);
      o[db] = __builtin_amdgcn_mfma_f32_32x32x16_bf16(vf0, pf10, o[db], 0, 0, 0);
      o[db] = __builtin_amdgcn_mfma_f32_32x32x16_bf16(vf1, pf11, o[db], 0, 0, 0);
    }
    __builtin_amdgcn_s_setprio(0);

    cur ^= 1;
  }

  float lsum = ps + __shfl_xor(ps, 32, 64);
  const int s = qrow0 + ln;
  const size_t rbase = ((size_t)((z * 16 + h) * 2048) + s) * 128;
#pragma unroll
  for (int db = 0; db < 4; db++)
#pragma unroll
    for (int rq = 0; rq < 4; rq++) {
      ushort4 v4;
      v4.x = f2h(o[db][rq * 4 + 0] * 0.0625f);   // /16 safety scale vs fp16 range
      v4.y = f2h(o[db][rq * 4 + 1] * 0.0625f);
      v4.z = f2h(o[db][rq * 4 + 2] * 0.0625f);
      v4.w = f2h(o[db][rq * 4 + 3] * 0.0625f);
      *(ushort4*)(&opart[rbase + db * 32 + 8 * rq + 4 * lh]) = v4;
    }
  if (lh == 0) ml[(size_t)(z * 16 + h) * 2048 + s] = lsum;
}

// ---------------- reduction v2: ushort2-vectorized, fp16 partials -> fp16 attn (z=2) ----------------
__global__ __launch_bounds__(256) void attn_reduce(const ush* __restrict__ opart,
                                                   const float* __restrict__ ml,
                                                   ush* __restrict__ attnh) {
  int row = blockIdx.x * 4 + (threadIdx.x >> 6);
  int l = threadIdx.x & 63;
  int h = row >> 11, s = row & 2047;
  float lsum = 0.f;
#pragma unroll
  for (int z = 0; z < 2; z++) lsum += ml[(size_t)(z * 16 + h) * 2048 + s];
  float inv = 16.0f / lsum;
  int c = l * 2;
  float a0 = 0.f, a1 = 0.f;
#pragma unroll
  for (int z = 0; z < 2; z++) {
    ushort2 v = *(const ushort2*)(&opart[((size_t)(z * 16 + h) * 2048 + s) * 128 + c]);
    a0 += h2f(v.x);
    a1 += h2f(v.y);
  }
  ushort2 o2;
  o2.x = f2h(bf2f(f2bf(a0 * inv)));
  o2.y = f2h(bf2f(f2bf(a1 * inv)));
  *(ushort2*)(&attnh[(size_t)s * 2048 + h * 128 + c]) = o2;
}

// ---------------- launch ----------------
extern "C" void kernel_launch(void* const* d_in, const int* in_sizes, int n_in,
                              void* d_out, int out_size, void* d_ws, size_t ws_size,
                              hipStream_t stream) {
  const float* x        = (const float*)d_in[0];
  const float* wq_down  = (const float*)d_in[1];
  const float* wq_up    = (const float*)d_in[2];
  const float* wq_rope  = (const float*)d_in[3];
  const float* wkv_down = (const float*)d_in[4];
  const float* wkv_up   = (const float*)d_in[5];
  const float* wk_rope  = (const float*)d_in[6];
  const float* wo       = (const float*)d_in[7];
  char* ws = (char*)d_ws;

  size_t off = 0;
  auto alloc = [&](size_t b) { size_t c = off; off += (b + 255) & ~(size_t)255; return c; };
  const size_t XH    = alloc(2048UL * 2048 * 2);      // x fp16 (aliased by ATTNH later)
  const size_t WDH   = alloc(1152UL * 2048 * 2);
  const size_t KRL   = alloc(2048UL * 64 * 4);
  const size_t CQH   = alloc(2048UL * 512 * 2);
  const size_t CKVH  = alloc(2048UL * 512 * 2);
  const size_t WQH   = alloc(3072UL * 512 * 2);
  const size_t QUPF  = alloc(2048UL * 3072 * 2);
  const size_t WKVUH = alloc(4096UL * 512 * 2);
  const size_t WOH   = alloc(2048UL * 2048 * 2);
  const size_t KVF   = alloc(2048UL * 4096 * 2);
  const size_t QB    = alloc(16UL * 2048 * 192 * 2);
  const size_t KBT   = alloc(16UL * 32 * 12800 * 2);
  const size_t VTT   = alloc(16UL * 32 * 9216 * 2);
  const size_t TAB   = alloc(2048UL * 32 * 4 * 2);
  const size_t OPART = alloc(2UL * 16 * 2048 * 128 * 2);  // fp16 partials (z=2)
  const size_t ML    = alloc(2UL * 16 * 2048 * 4);
  const size_t ATTNH = XH;  // x fp16 dead after down-proj

  // mega pack: 3604480 quad-threads + 65536 rope = 3670016 threads = 14336 blocks
  mega_pack<<<dim3(14336), 256, 0, stream>>>(
      wq_down, wkv_down, wk_rope, wq_up, wq_rope, wkv_up, wo, x,
      (ush*)(ws + WDH), (ush*)(ws + WQH), (ush*)(ws + WKVUH),
      (ush*)(ws + WOH), (ush*)(ws + XH), (float*)(ws + TAB));

  // down: (2048x2048)*(1152x2048)^T -> fp16 cq/ckv + f32 krl, 128x64 tiles
  gemm_down<<<dim3(18, 16), 256, 0, stream>>>(
      (ush*)(ws + XH), (ush*)(ws + WDH),
      (ush*)(ws + CQH), (ush*)(ws + CKVH), (float*)(ws + KRL));

  // merged q-up + kv-up (one launch, 1792 blocks)
  gemm_up<<<dim3(112, 16), 256, 0, stream>>>(
      (ush*)(ws + CQH), (ush*)(ws + WQH),
      (ush*)(ws + CKVH), (ush*)(ws + WKVUH),
      (ush*)(ws + QUPF), (ush*)(ws + KVF));

  // builders v2: 6272 elementwise blocks + 512 vtrans = 6784
  build_all<<<dim3(6784), 256, 0, stream>>>(
      (const ush*)(ws + QUPF), (const ush*)(ws + KVF), (const float*)(ws + KRL),
      (const float*)(ws + TAB), (ush*)(ws + QB), (ush*)(ws + KBT), (ush*)(ws + VTT));

  // attn: 256 blocks (8 qx x 16 h x z=2), 512 threads
  attn_fused<<<dim3(8, 16, 2), 512, 0, stream>>>(
      (ush*)(ws + QB), (ush*)(ws + KBT), (ush*)(ws + VTT),
      (ush*)(ws + OPART), (float*)(ws + ML));
  attn_reduce<<<dim3(8192), 256, 0, stream>>>((const ush*)(ws + OPART), (const float*)(ws + ML),
                                              (ush*)(ws + ATTNH));

  // out: (2048x2048)*(2048x2048)^T -> d_out f32
  gemm_out<<<dim3(32, 16), 256, 0, stream>>>(
      (ush*)(ws + ATTNH), (ush*)(ws + WOH), (float*)d_out, 2048, 2048);
}

// Round 13
// 269.987 us; speedup vs baseline: 1.1888x; 1.0251x over previous
//
#include <hip/hip_runtime.h>
#include <stdint.h>
#include <math.h>

#define S_LEN 2048
#define NH 16

typedef __attribute__((ext_vector_type(8))) short bf16x8;
typedef __attribute__((ext_vector_type(4))) float f32x4;
typedef __attribute__((ext_vector_type(16))) float f32x16;
typedef unsigned short ush;

__device__ __forceinline__ ush f2bf(float f) {   // RNE float->bf16
  union { float f; unsigned u; } v; v.f = f;
  unsigned x = v.u;
  return (ush)((x + 0x7fffu + ((x >> 16) & 1u)) >> 16);
}
__device__ __forceinline__ float bf2f(ush b) {
  union { unsigned u; float f; } v; v.u = ((unsigned)b) << 16;
  return v.f;
}
__device__ __forceinline__ ush f2h(float f) {    // RNE float->fp16
  _Float16 h = (_Float16)f;
  union { _Float16 h; ush u; } v; v.h = h;
  return v.u;
}
__device__ __forceinline__ float h2f(ush u) {
  union { ush u; _Float16 h; } v; v.u = u;
  return (float)v.h;
}

// async global->LDS, 16B/lane; LDS dest = wave-uniform base + lane*16
__device__ __forceinline__ void gload_lds16(const ush* g, ush* l) {
  __builtin_amdgcn_global_load_lds((const __attribute__((address_space(1))) void*)g,
                                   (__attribute__((address_space(3))) void*)l, 16, 0, 0);
}

// ---------------- mega pack v2: float4-vectorized (4 elem/thread), ONE launch ----------------
__global__ void mega_pack(const float* __restrict__ wq_down, const float* __restrict__ wkv_down,
                          const float* __restrict__ wk_rope, const float* __restrict__ wq_up,
                          const float* __restrict__ wq_rope, const float* __restrict__ wkv_up,
                          const float* __restrict__ wo, const float* __restrict__ x,
                          ush* __restrict__ wdh, ush* __restrict__ wqh, ush* __restrict__ wkvuh,
                          ush* __restrict__ woh, ush* __restrict__ xh, float* __restrict__ tab) {
  int idx = blockIdx.x * 256 + threadIdx.x;
  if (idx < 3604480) {        // quad-converters: 14417920 f32 elements / 4
    int qi = idx * 4;
    if (qi < 2359296) {       // fused down weights [wq_down|wkv_down|wk_rope|0] 1152x2048
      int r = qi >> 11, c = qi & 2047;
      float4 v = {0.f, 0.f, 0.f, 0.f};
      if (r < 512)       v = *(const float4*)(wq_down + (size_t)r * 2048 + c);
      else if (r < 1024) v = *(const float4*)(wkv_down + (size_t)(r - 512) * 2048 + c);
      else if (r < 1088) v = *(const float4*)(wk_rope + (size_t)(r - 1024) * 2048 + c);
      ushort4 o4; o4.x = f2h(v.x); o4.y = f2h(v.y); o4.z = f2h(v.z); o4.w = f2h(v.w);
      *(ushort4*)(wdh + qi) = o4;
      return;
    }
    qi -= 2359296;
    if (qi < 1572864) {       // fused [wq_up|wq_rope] 3072x512
      int r = qi >> 9, c = qi & 511;
      const float* src = (r < 2048) ? wq_up + (size_t)r * 512 + c
                                    : wq_rope + (size_t)(r - 2048) * 512 + c;
      float4 v = *(const float4*)src;
      ushort4 o4; o4.x = f2h(v.x); o4.y = f2h(v.y); o4.z = f2h(v.z); o4.w = f2h(v.w);
      *(ushort4*)(wqh + qi) = o4;
      return;
    }
    qi -= 1572864;
    if (qi < 2097152) {       // wkv_up 4096x512
      float4 v = *(const float4*)(wkv_up + qi);
      ushort4 o4; o4.x = f2h(v.x); o4.y = f2h(v.y); o4.z = f2h(v.z); o4.w = f2h(v.w);
      *(ushort4*)(wkvuh + qi) = o4;
      return;
    }
    qi -= 2097152;
    if (qi < 4194304) {       // wo 2048x2048
      float4 v = *(const float4*)(wo + qi);
      ushort4 o4; o4.x = f2h(v.x); o4.y = f2h(v.y); o4.z = f2h(v.z); o4.w = f2h(v.w);
      *(ushort4*)(woh + qi) = o4;
      return;
    }
    qi -= 4194304;
    {                         // x 2048x2048
      float4 v = *(const float4*)(x + qi);
      ushort4 o4; o4.x = f2h(v.x); o4.y = f2h(v.y); o4.z = f2h(v.z); o4.w = f2h(v.w);
      *(ushort4*)(xh + qi) = o4;
      return;
    }
  }
  idx -= 3604480;
  if (idx < 65536) {  // rope table
    int tt = idx >> 5, i = idx & 31;
    float inv_freq = 1.0f / powf(10000.0f, (float)i * (1.0f / 32.0f));
    float fr = (float)tt * inv_freq;
    tab[idx] = sinf(fr);
    tab[65536 + idx] = cosf(fr);
  }
}

// ---------------- down GEMM v2: BM=128,BN=64,K=2048, single-barrier dbuf, fused epilogue ----------------
__global__ __launch_bounds__(256) void gemm_down(
    const ush* __restrict__ A, const ush* __restrict__ B,
    ush* __restrict__ cqh, ush* __restrict__ ckvh, float* __restrict__ krl) {
  constexpr int BM = 128, BN = 64, K = 2048, FI = 4, FJ = 2;
  __shared__ __align__(16) ush As[2 * BM * 32];
  __shared__ __align__(16) ush Bs[2 * BN * 32];
  const int t = threadIdx.x, l = t & 63, w = t >> 6;
  const int wm = w & 1, wn = w >> 1;
  const int m0 = blockIdx.y * BM, n0 = blockIdx.x * BN;
  const int lm = l & 15, lq = l >> 4;
  const int lr = l >> 2, lc = (l & 3) * 8;

  f32x4 acc[FI][FJ];
  const f32x4 zero = {0.f, 0.f, 0.f, 0.f};
#pragma unroll
  for (int i = 0; i < FI; i++)
#pragma unroll
    for (int j = 0; j < FJ; j++) acc[i][j] = zero;

  const ush* Ag[2];
#pragma unroll
  for (int i = 0; i < 2; i++) Ag[i] = A + (size_t)(m0 + w * 32 + i * 16 + lr) * K + lc;
  const ush* Bg = B + (size_t)(n0 + w * 16 + lr) * K + lc;

#pragma unroll
  for (int i = 0; i < 2; i++) gload_lds16(Ag[i], As + w * 1024 + i * 512);
  gload_lds16(Bg, Bs + w * 512);

  int cur = 0;
  for (int k0 = 0; k0 < K; k0 += 32) {
    asm volatile("s_waitcnt vmcnt(0)" ::: "memory");
    __builtin_amdgcn_s_barrier();
    __builtin_amdgcn_sched_barrier(0);
    if (k0 + 32 < K) {
      int nb = cur ^ 1;
#pragma unroll
      for (int i = 0; i < 2; i++)
        gload_lds16(Ag[i] + k0 + 32, As + nb * 4096 + w * 1024 + i * 512);
      gload_lds16(Bg + k0 + 32, Bs + nb * 2048 + w * 512);
    }
    __builtin_amdgcn_sched_barrier(0);
    const ush* Asc = As + cur * 4096;
    const ush* Bsc = Bs + cur * 2048;
    bf16x8 af[FI], bfr[FJ];
#pragma unroll
    for (int i = 0; i < FI; i++)
      af[i] = *(const bf16x8*)(Asc + (wm * 64 + i * 16 + lm) * 32 + lq * 8);
#pragma unroll
    for (int j = 0; j < FJ; j++)
      bfr[j] = *(const bf16x8*)(Bsc + (wn * 32 + j * 16 + lm) * 32 + lq * 8);
#pragma unroll
    for (int i = 0; i < FI; i++)
#pragma unroll
      for (int j = 0; j < FJ; j++)
        acc[i][j] = __builtin_amdgcn_mfma_f32_16x16x32_f16(af[i], bfr[j], acc[i][j], 0, 0, 0);
    cur ^= 1;
  }

#pragma unroll
  for (int i = 0; i < FI; i++)
#pragma unroll
    for (int j = 0; j < FJ; j++)
#pragma unroll
      for (int r = 0; r < 4; r++) {
        int mm = m0 + wm * 64 + i * 16 + lq * 4 + r;
        int nn = n0 + wn * 32 + j * 16 + lm;
        float v = acc[i][j][r];
        if (nn < 512)       cqh[(size_t)mm * 512 + nn] = f2h(v);
        else if (nn < 1024) ckvh[(size_t)mm * 512 + nn - 512] = f2h(v);
        else if (nn < 1088) krl[(size_t)mm * 64 + nn - 1024] = v;
      }
}

// ---------------- merged up GEMM (qup blocks [0,24), kvup [24,56)): BM=128,BN=128,K=512,
// single-barrier dbuf, 4x4 frag (higher AI: 64 B/KFLOP LDS vs 96), fp16 out ----------------
__global__ __launch_bounds__(256) void gemm_up(
    const ush* __restrict__ cqh, const ush* __restrict__ wqh,
    const ush* __restrict__ ckvh, const ush* __restrict__ wkvuh,
    ush* __restrict__ qupf, ush* __restrict__ kvf) {
  constexpr int K = 512, FI = 4, FJ = 4;
  __shared__ __align__(16) ush As[2 * 128 * 32];
  __shared__ __align__(16) ush Bs[2 * 128 * 32];
  int bx = blockIdx.x;
  const ush* A; const ush* B; ush* C; int ldc;
  if (bx < 24) { A = cqh; B = wqh; C = qupf; ldc = 3072; }
  else { bx -= 24; A = ckvh; B = wkvuh; C = kvf; ldc = 4096; }
  const int t = threadIdx.x, l = t & 63, w = t >> 6;
  const int wm = w & 1, wn = w >> 1;
  const int m0 = blockIdx.y * 128, n0 = bx * 128;
  const int lm = l & 15, lq = l >> 4;
  const int lr = l >> 2, lc = (l & 3) * 8;

  f32x4 acc[FI][FJ];
  const f32x4 zero = {0.f, 0.f, 0.f, 0.f};
#pragma unroll
  for (int i = 0; i < FI; i++)
#pragma unroll
    for (int j = 0; j < FJ; j++) acc[i][j] = zero;

  const ush* Ag[2]; const ush* Bg[2];
#pragma unroll
  for (int i = 0; i < 2; i++) {
    Ag[i] = A + (size_t)(m0 + w * 32 + i * 16 + lr) * K + lc;
    Bg[i] = B + (size_t)(n0 + w * 32 + i * 16 + lr) * K + lc;
  }

#pragma unroll
  for (int i = 0; i < 2; i++) {
    gload_lds16(Ag[i], As + w * 1024 + i * 512);
    gload_lds16(Bg[i], Bs + w * 1024 + i * 512);
  }

  int cur = 0;
  for (int k0 = 0; k0 < K; k0 += 32) {
    asm volatile("s_waitcnt vmcnt(0)" ::: "memory");
    __builtin_amdgcn_s_barrier();
    __builtin_amdgcn_sched_barrier(0);
    if (k0 + 32 < K) {
      int nb = cur ^ 1;
#pragma unroll
      for (int i = 0; i < 2; i++) {
        gload_lds16(Ag[i] + k0 + 32, As + nb * 4096 + w * 1024 + i * 512);
        gload_lds16(Bg[i] + k0 + 32, Bs + nb * 4096 + w * 1024 + i * 512);
      }
    }
    __builtin_amdgcn_sched_barrier(0);
    const ush* Asc = As + cur * 4096;
    const ush* Bsc = Bs + cur * 4096;
    bf16x8 af[FI], bfr[FJ];
#pragma unroll
    for (int i = 0; i < FI; i++)
      af[i] = *(const bf16x8*)(Asc + (wm * 64 + i * 16 + lm) * 32 + lq * 8);
#pragma unroll
    for (int j = 0; j < FJ; j++)
      bfr[j] = *(const bf16x8*)(Bsc + (wn * 64 + j * 16 + lm) * 32 + lq * 8);
#pragma unroll
    for (int i = 0; i < FI; i++)
#pragma unroll
      for (int j = 0; j < FJ; j++)
        acc[i][j] = __builtin_amdgcn_mfma_f32_16x16x32_f16(af[i], bfr[j], acc[i][j], 0, 0, 0);
    cur ^= 1;
  }

#pragma unroll
  for (int i = 0; i < FI; i++)
#pragma unroll
    for (int j = 0; j < FJ; j++)
#pragma unroll
      for (int r = 0; r < 4; r++) {
        int mm = m0 + wm * 64 + i * 16 + lq * 4 + r;
        int nn = n0 + wn * 64 + j * 16 + lm;
        C[(size_t)mm * ldc + nn] = f2h(acc[i][j][r]);
      }
}

// ---------------- out GEMM: BM=128,BN=64, single-barrier dbuf, f32 out ----------------
__global__ __launch_bounds__(256) void gemm_out(
    const ush* __restrict__ A, const ush* __restrict__ B, float* __restrict__ C,
    int K, int ldc) {
  constexpr int BM = 128, BN = 64, FI = 4, FJ = 2;
  __shared__ __align__(16) ush As[2 * BM * 32];
  __shared__ __align__(16) ush Bs[2 * BN * 32];
  const int t = threadIdx.x, l = t & 63, w = t >> 6;
  const int wm = w & 1, wn = w >> 1;
  const int m0 = blockIdx.y * BM, n0 = blockIdx.x * BN;
  const int lm = l & 15, lq = l >> 4;
  const int lr = l >> 2, lc = (l & 3) * 8;

  f32x4 acc[FI][FJ];
  const f32x4 zero = {0.f, 0.f, 0.f, 0.f};
#pragma unroll
  for (int i = 0; i < FI; i++)
#pragma unroll
    for (int j = 0; j < FJ; j++) acc[i][j] = zero;

  const ush* Ag[2];
#pragma unroll
  for (int i = 0; i < 2; i++) Ag[i] = A + (size_t)(m0 + w * 32 + i * 16 + lr) * K + lc;
  const ush* Bg = B + (size_t)(n0 + w * 16 + lr) * K + lc;

#pragma unroll
  for (int i = 0; i < 2; i++) gload_lds16(Ag[i], As + w * 1024 + i * 512);
  gload_lds16(Bg, Bs + w * 512);

  int cur = 0;
  for (int k0 = 0; k0 < K; k0 += 32) {
    asm volatile("s_waitcnt vmcnt(0)" ::: "memory");
    __builtin_amdgcn_s_barrier();
    __builtin_amdgcn_sched_barrier(0);
    if (k0 + 32 < K) {
      int nb = cur ^ 1;
#pragma unroll
      for (int i = 0; i < 2; i++)
        gload_lds16(Ag[i] + k0 + 32, As + nb * 4096 + w * 1024 + i * 512);
      gload_lds16(Bg + k0 + 32, Bs + nb * 2048 + w * 512);
    }
    __builtin_amdgcn_sched_barrier(0);
    const ush* Asc = As + cur * 4096;
    const ush* Bsc = Bs + cur * 2048;
    bf16x8 af[FI], bfr[FJ];
#pragma unroll
    for (int i = 0; i < FI; i++)
      af[i] = *(const bf16x8*)(Asc + (wm * 64 + i * 16 + lm) * 32 + lq * 8);
#pragma unroll
    for (int j = 0; j < FJ; j++)
      bfr[j] = *(const bf16x8*)(Bsc + (wn * 32 + j * 16 + lm) * 32 + lq * 8);
#pragma unroll
    for (int i = 0; i < FI; i++)
#pragma unroll
      for (int j = 0; j < FJ; j++)
        acc[i][j] = __builtin_amdgcn_mfma_f32_16x16x32_f16(af[i], bfr[j], acc[i][j], 0, 0, 0);
    cur ^= 1;
  }

#pragma unroll
  for (int i = 0; i < FI; i++)
#pragma unroll
    for (int j = 0; j < FJ; j++)
#pragma unroll
      for (int r = 0; r < 4; r++) {
        int mm = m0 + wm * 64 + i * 16 + lq * 4 + r;
        int nn = n0 + wn * 32 + j * 16 + lm;
        C[(size_t)mm * ldc + nn] = acc[i][j][r];
      }
}

// ---------------- builders v2: 8-wide vectorized qb + kbt, vtrans unchanged ----------------
__global__ void build_all(const ush* __restrict__ qupf, const ush* __restrict__ kvf,
                          const float* __restrict__ krl, const float* __restrict__ tab,
                          ush* __restrict__ qb, ush* __restrict__ kbt, ush* __restrict__ vtt) {
  const float scale = 0.07216878364870323f;  // 1/sqrt(192), folded into q
  if (blockIdx.x >= 6272) {  // vtrans: (s,d) fp16 -> (h,T,d[128],c[72]) bf16
    __shared__ ush Vt[128 * 72];
    int b = blockIdx.x - 6272;
    const int T = b & 31, h = b >> 5, t = threadIdx.x;
    const int key = t >> 5, d0 = (t & 31) * 4;
#pragma unroll
    for (int pass = 0; pass < 8; ++pass) {
      int k = key + pass * 8;
      int s = T * 64 + k;
      ushort4 v = *(const ushort4*)(kvf + (size_t)s * 4096 + 2048 + h * 128 + d0);
      Vt[(d0 + 0) * 72 + k] = f2bf(h2f(v.x));
      Vt[(d0 + 1) * 72 + k] = f2bf(h2f(v.y));
      Vt[(d0 + 2) * 72 + k] = f2bf(h2f(v.z));
      Vt[(d0 + 3) * 72 + k] = f2bf(h2f(v.w));
    }
    __syncthreads();
    ush* dst = vtt + (size_t)(h * 32 + T) * 9216;
    for (int off = t; off < 1152; off += 256) {
      int row = off / 9, c8 = (off % 9) * 8;
      *(bf16x8*)(dst + row * 72 + c8) = *(const bf16x8*)(Vt + row * 72 + c8);
    }
    return;
  }
  int idx = blockIdx.x * 256 + threadIdx.x;
  if (idx < 786432) {  // qb (h,s,192) 8-wide: 24 groups per (h,s)
    int g = idx % 24; int sh = idx / 24; int h = sh & 15; int s = sh >> 4;
    int d0 = g * 8;
    union { ush u[8]; bf16x8 v; } out;
    if (d0 < 128) {
      bf16x8 src = *(const bf16x8*)(qupf + (size_t)s * 3072 + h * 128 + d0);
#pragma unroll
      for (int e = 0; e < 8; e++) out.u[e] = f2bf(h2f((ush)src[e]) * scale);
    } else {
      int r = d0 - 128;           // multiple of 8; whole group in one rope half
      int i0 = r & 31;
      const ush* qr = qupf + (size_t)s * 3072 + 2048 + h * 64;
      bf16x8 xv = *(const bf16x8*)(qr + r);
      bf16x8 ov = (r < 32) ? *(const bf16x8*)(qr + r + 32) : *(const bf16x8*)(qr + r - 32);
      float4 sn0 = *(const float4*)(tab + s * 32 + i0);
      float4 sn1 = *(const float4*)(tab + s * 32 + i0 + 4);
      float4 cs0 = *(const float4*)(tab + 65536 + s * 32 + i0);
      float4 cs1 = *(const float4*)(tab + 65536 + s * 32 + i0 + 4);
      float sn[8] = {sn0.x, sn0.y, sn0.z, sn0.w, sn1.x, sn1.y, sn1.z, sn1.w};
      float cs[8] = {cs0.x, cs0.y, cs0.z, cs0.w, cs1.x, cs1.y, cs1.z, cs1.w};
#pragma unroll
      for (int e = 0; e < 8; e++) {
        float x = h2f((ush)xv[e]);
        float other = (r < 32) ? -h2f((ush)ov[e]) : h2f((ush)ov[e]);
        out.u[e] = f2bf((x * cs[e] + other * sn[e]) * scale);
      }
    }
    *(bf16x8*)(qb + ((size_t)h * S_LEN + s) * 192 + d0) = out.v;
    return;
  }
  idx -= 786432;
  {  // kbt (h,T,key[64],c[200]) 8-wide: 25 groups per row
    int g = idx % 25; int row = idx / 25;
    int key = row & 63; int r3 = row >> 6; int T = r3 & 31; int h = r3 >> 5;
    int s = T * 64 + key;
    int c0 = g * 8;
    union { ush u[8]; bf16x8 v; } out;
    if (c0 < 128) {
      bf16x8 src = *(const bf16x8*)(kvf + (size_t)s * 4096 + h * 128 + c0);
#pragma unroll
      for (int e = 0; e < 8; e++) out.u[e] = f2bf(h2f((ush)src[e]));
    } else if (c0 < 192) {
      int r = c0 - 128;           // multiple of 8; whole group in one rope half
      int i0 = r & 31;
      const float* kr = krl + (size_t)s * 64;
      float4 xv0 = *(const float4*)(kr + r);
      float4 xv1 = *(const float4*)(kr + r + 4);
      const float* kro = (r < 32) ? kr + r + 32 : kr + r - 32;
      float4 ov0 = *(const float4*)(kro);
      float4 ov1 = *(const float4*)(kro + 4);
      float4 sn0 = *(const float4*)(tab + s * 32 + i0);
      float4 sn1 = *(const float4*)(tab + s * 32 + i0 + 4);
      float4 cs0 = *(const float4*)(tab + 65536 + s * 32 + i0);
      float4 cs1 = *(const float4*)(tab + 65536 + s * 32 + i0 + 4);
      float xv[8] = {xv0.x, xv0.y, xv0.z, xv0.w, xv1.x, xv1.y, xv1.z, xv1.w};
      float ov[8] = {ov0.x, ov0.y, ov0.z, ov0.w, ov1.x, ov1.y, ov1.z, ov1.w};
      float sn[8] = {sn0.x, sn0.y, sn0.z, sn0.w, sn1.x, sn1.y, sn1.z, sn1.w};
      float cs[8] = {cs0.x, cs0.y, cs0.z, cs0.w, cs1.x, cs1.y, cs1.z, cs1.w};
#pragma unroll
      for (int e = 0; e < 8; e++) {
        float other = (r < 32) ? -ov[e] : ov[e];
        out.u[e] = f2bf(xv[e] * cs[e] + other * sn[e]);
      }
    } else {
#pragma unroll
      for (int e = 0; e < 8; e++) out.u[e] = 0;
    }
    *(bf16x8*)(kbt + ((size_t)(h * 32 + T) * 64 + key) * 200 + c0) = out.v;
  }
}

// ---------------- flash attention (exact R3 body): single barrier/iter, dbuf K+V,
// prefetch-after-barrier, QK0-SM0-QK1-PV0-SM1-PV1 interleave, __expf, permlane32_swap, z=2 ----------------
__global__ __launch_bounds__(512, 2) void attn_fused(
    const ush* __restrict__ qb, const ush* __restrict__ kbt, const ush* __restrict__ vtt,
    ush* __restrict__ opart, float* __restrict__ ml) {
  __shared__ __align__(16) ush Ks[2][64 * 200];   // 2 x 25.6 KB
  __shared__ __align__(16) ush Vs[2][128 * 72];   // 2 x 18.4 KB  (88 KB total)
  const int t = threadIdx.x, l = t & 63, w = t >> 6;   // 8 waves
  const int id = blockIdx.x + 8 * (blockIdx.y + 16 * blockIdx.z);
  const int wid = (id & 7) * 32 + (id >> 3);
  const int qx = wid & 7, h = (wid >> 3) & 15, z = wid >> 7;
  const int qrow0 = qx * 256 + w * 32;
  const int ln = l & 31, lh = l >> 5;

  bf16x8 qf[12];
#pragma unroll
  for (int st = 0; st < 12; st++)
    qf[st] = *(const bf16x8*)(qb + ((size_t)h * S_LEN + qrow0 + ln) * 192 + st * 16 + lh * 8);
#pragma unroll
  for (int st = 0; st < 12; st++) asm volatile("" : "+v"(qf[st]));

  f32x16 o[4];
#pragma unroll
  for (int i = 0; i < 4; i++)
#pragma unroll
    for (int r = 0; r < 16; r++) o[i][r] = 0.f;
  float ps = 0.f;  // per-lane sum of exp; partner lane (l^32) holds other half

  const ush* kbase = kbt + (size_t)(h * 32 + z * 16) * 12800;
  const ush* vbase = vtt + (size_t)(h * 32 + z * 16) * 9216;

  // softmax pack: sv (16 scores) -> exp -> bf16 pairs -> lane^32 half-exchange
  auto smpack = [&ps](const f32x16& svv, bf16x8& f0, bf16x8& f1) {
    unsigned pk8[8];
#pragma unroll
    for (int g = 0; g < 4; g++) {
      float p0 = __expf(svv[4 * g + 0]);   // scale pre-folded into q
      float p1 = __expf(svv[4 * g + 1]);
      float p2 = __expf(svv[4 * g + 2]);
      float p3 = __expf(svv[4 * g + 3]);
      ps += (p0 + p1) + (p2 + p3);
      unsigned lo, hi;
      asm("v_cvt_pk_bf16_f32 %0, %1, %2" : "=v"(lo) : "v"(p0), "v"(p1));
      asm("v_cvt_pk_bf16_f32 %0, %1, %2" : "=v"(hi) : "v"(p2), "v"(p3));
      pk8[2 * g] = lo; pk8[2 * g + 1] = hi;
    }
    asm("v_permlane32_swap_b32 %0, %1" : "+v"(pk8[0]), "+v"(pk8[2]));
    asm("v_permlane32_swap_b32 %0, %1" : "+v"(pk8[1]), "+v"(pk8[3]));
    asm("v_permlane32_swap_b32 %0, %1" : "+v"(pk8[4]), "+v"(pk8[6]));
    asm("v_permlane32_swap_b32 %0, %1" : "+v"(pk8[5]), "+v"(pk8[7]));
    union { unsigned d[4]; bf16x8 v; } u0, u1;
    u0.d[0] = pk8[0]; u0.d[1] = pk8[1]; u0.d[2] = pk8[2]; u0.d[3] = pk8[3];
    u1.d[0] = pk8[4]; u1.d[1] = pk8[5]; u1.d[2] = pk8[6]; u1.d[3] = pk8[7];
    f0 = u0.v; f1 = u1.v;
  };

  // prologue: stage tile 0 into buf 0 (43 chunks of 1 KB over 8 waves)
  for (int c = w; c < 43; c += 8) {
    if (c < 25) gload_lds16(kbase + c * 512 + l * 8, &Ks[0][c * 512]);
    else        gload_lds16(vbase + (c - 25) * 512 + l * 8, &Vs[0][(c - 25) * 512]);
  }

  int cur = 0;
  for (int it = 0; it < 16; ++it) {
    // drain own loads for tile it (issued a full iteration ago), then publish
    asm volatile("s_waitcnt vmcnt(0)" ::: "memory");
    __builtin_amdgcn_s_barrier();
    __builtin_amdgcn_sched_barrier(0);
    // issue next-tile prefetch AFTER the barrier; stays in flight under this iter's compute
    if (it < 15) {
      const ush* ksrc = kbase + (size_t)(it + 1) * 12800;
      const ush* vsrc = vbase + (size_t)(it + 1) * 9216;
      ush* kd = &Ks[cur ^ 1][0];
      ush* vd = &Vs[cur ^ 1][0];
      for (int c = w; c < 43; c += 8) {
        if (c < 25) gload_lds16(ksrc + c * 512 + l * 8, kd + c * 512);
        else        gload_lds16(vsrc + (c - 25) * 512 + l * 8, vd + (c - 25) * 512);
      }
    }
    __builtin_amdgcn_sched_barrier(0);

    const ush* Kb = &Ks[cur][0];
    const ush* Vb = &Vs[cur][0];

    f32x16 sv0, sv1;
#pragma unroll
    for (int r = 0; r < 16; r++) { sv0[r] = 0.f; sv1[r] = 0.f; }

    // QK kb0
    __builtin_amdgcn_s_setprio(1);
#pragma unroll
    for (int st = 0; st < 12; st++) {
      bf16x8 af = *(const bf16x8*)(Kb + ln * 200 + st * 16 + lh * 8);
      sv0 = __builtin_amdgcn_mfma_f32_32x32x16_bf16(af, qf[st], sv0, 0, 0, 0);
    }
    __builtin_amdgcn_s_setprio(0);

    // SM kb0 (VALU) — overlaps QK kb1 (MFMA)
    bf16x8 pf00, pf01;
    smpack(sv0, pf00, pf01);

    // QK kb1
    __builtin_amdgcn_s_setprio(1);
#pragma unroll
    for (int st = 0; st < 12; st++) {
      bf16x8 af = *(const bf16x8*)(Kb + (32 + ln) * 200 + st * 16 + lh * 8);
      sv1 = __builtin_amdgcn_mfma_f32_32x32x16_bf16(af, qf[st], sv1, 0, 0, 0);
    }
    __builtin_amdgcn_s_setprio(0);

    // PV kb0
    __builtin_amdgcn_s_setprio(1);
#pragma unroll
    for (int db = 0; db < 4; db++) {
      bf16x8 vf0 = *(const bf16x8*)(Vb + (db * 32 + ln) * 72 + lh * 8);
      bf16x8 vf1 = *(const bf16x8*)(Vb + (db * 32 + ln) * 72 + 16 + lh * 8);
      o[db] = __builtin_amdgcn_mfma_f32_32x32x16_bf16(vf0, pf00, o[db], 0, 0, 0);
      o[db] = __builtin_amdgcn_mfma_f32_32x32x16_bf16(vf1, pf01, o[db], 0, 0, 0);
    }
    __builtin_amdgcn_s_setprio(0);

    // SM kb1
    bf16x8 pf10, pf11;
    smpack(sv1, pf10, pf11);

    // PV kb1
    __builtin_amdgcn_s_setprio(1);
#pragma unroll
    for (int db = 0; db < 4; db++) {
      bf16x8 vf0 = *(const bf16x8*)(Vb + (db * 32 + ln) * 72 + 32 + lh * 8);
      bf16x8 vf1 = *(const bf16x8*)(Vb + (db * 32 + ln) * 72 + 48 + lh * 8);
      o[db] = __builtin_amdgcn_mfma_f32_32x32x16_bf16(vf0, pf10, o[db], 0, 0, 0);
      o[db] = __builtin_amdgcn_mfma_f32_32x32x16_bf16(vf1, pf11, o[db], 0, 0, 0);
    }
    __builtin_amdgcn_s_setprio(0);

    cur ^= 1;
  }

  float lsum = ps + __shfl_xor(ps, 32, 64);
  const int s = qrow0 + ln;
  const size_t rbase = ((size_t)((z * 16 + h) * 2048) + s) * 128;
#pragma unroll
  for (int db = 0; db < 4; db++)
#pragma unroll
    for (int rq = 0; rq < 4; rq++) {
      ushort4 v4;
      v4.x = f2h(o[db][rq * 4 + 0] * 0.0625f);   // /16 safety scale vs fp16 range
      v4.y = f2h(o[db][rq * 4 + 1] * 0.0625f);
      v4.z = f2h(o[db][rq * 4 + 2] * 0.0625f);
      v4.w = f2h(o[db][rq * 4 + 3] * 0.0625f);
      *(ushort4*)(&opart[rbase + db * 32 + 8 * rq + 4 * lh]) = v4;
    }
  if (lh == 0) ml[(size_t)(z * 16 + h) * 2048 + s] = lsum;
}

// ---------------- reduction v3: ushort4-vectorized (8B/lane), fp16 partials -> fp16 attn (z=2) ----------------
__global__ __launch_bounds__(256) void attn_reduce(const ush* __restrict__ opart,
                                                   const float* __restrict__ ml,
                                                   ush* __restrict__ attnh) {
  int row = blockIdx.x * 8 + (threadIdx.x >> 5);   // 32 lanes per 128-col row
  int lane = threadIdx.x & 31;
  int h = row >> 11, s = row & 2047;
  float lsum = 0.f;
#pragma unroll
  for (int z = 0; z < 2; z++) lsum += ml[(size_t)(z * 16 + h) * 2048 + s];
  float inv = 16.0f / lsum;
  int c = lane * 4;
  float a[4] = {0.f, 0.f, 0.f, 0.f};
#pragma unroll
  for (int z = 0; z < 2; z++) {
    ushort4 v = *(const ushort4*)(&opart[((size_t)(z * 16 + h) * 2048 + s) * 128 + c]);
    a[0] += h2f(v.x); a[1] += h2f(v.y); a[2] += h2f(v.z); a[3] += h2f(v.w);
  }
  ushort4 o4;
  o4.x = f2h(bf2f(f2bf(a[0] * inv)));
  o4.y = f2h(bf2f(f2bf(a[1] * inv)));
  o4.z = f2h(bf2f(f2bf(a[2] * inv)));
  o4.w = f2h(bf2f(f2bf(a[3] * inv)));
  *(ushort4*)(&attnh[(size_t)s * 2048 + h * 128 + c]) = o4;
}

// ---------------- launch ----------------
extern "C" void kernel_launch(void* const* d_in, const int* in_sizes, int n_in,
                              void* d_out, int out_size, void* d_ws, size_t ws_size,
                              hipStream_t stream) {
  const float* x        = (const float*)d_in[0];
  const float* wq_down  = (const float*)d_in[1];
  const float* wq_up    = (const float*)d_in[2];
  const float* wq_rope  = (const float*)d_in[3];
  const float* wkv_down = (const float*)d_in[4];
  const float* wkv_up   = (const float*)d_in[5];
  const float* wk_rope  = (const float*)d_in[6];
  const float* wo       = (const float*)d_in[7];
  char* ws = (char*)d_ws;

  size_t off = 0;
  auto alloc = [&](size_t b) { size_t c = off; off += (b + 255) & ~(size_t)255; return c; };
  const size_t XH    = alloc(2048UL * 2048 * 2);      // x fp16 (aliased by ATTNH later)
  const size_t WDH   = alloc(1152UL * 2048 * 2);
  const size_t KRL   = alloc(2048UL * 64 * 4);
  const size_t CQH   = alloc(2048UL * 512 * 2);
  const size_t CKVH  = alloc(2048UL * 512 * 2);
  const size_t WQH   = alloc(3072UL * 512 * 2);
  const size_t QUPF  = alloc(2048UL * 3072 * 2);
  const size_t WKVUH = alloc(4096UL * 512 * 2);
  const size_t WOH   = alloc(2048UL * 2048 * 2);
  const size_t KVF   = alloc(2048UL * 4096 * 2);
  const size_t QB    = alloc(16UL * 2048 * 192 * 2);
  const size_t KBT   = alloc(16UL * 32 * 12800 * 2);
  const size_t VTT   = alloc(16UL * 32 * 9216 * 2);
  const size_t TAB   = alloc(2048UL * 32 * 4 * 2);
  const size_t OPART = alloc(2UL * 16 * 2048 * 128 * 2);  // fp16 partials (z=2)
  const size_t ML    = alloc(2UL * 16 * 2048 * 4);
  const size_t ATTNH = XH;  // x fp16 dead after down-proj

  // mega pack: 3604480 quad-threads + 65536 rope = 3670016 threads = 14336 blocks
  mega_pack<<<dim3(14336), 256, 0, stream>>>(
      wq_down, wkv_down, wk_rope, wq_up, wq_rope, wkv_up, wo, x,
      (ush*)(ws + WDH), (ush*)(ws + WQH), (ush*)(ws + WKVUH),
      (ush*)(ws + WOH), (ush*)(ws + XH), (float*)(ws + TAB));

  // down: (2048x2048)*(1152x2048)^T -> fp16 cq/ckv + f32 krl, 128x64 tiles
  gemm_down<<<dim3(18, 16), 256, 0, stream>>>(
      (ush*)(ws + XH), (ush*)(ws + WDH),
      (ush*)(ws + CQH), (ush*)(ws + CKVH), (float*)(ws + KRL));

  // merged q-up + kv-up, 128x128 tiles (qup 24 bx, kvup 32 bx; 896 blocks)
  gemm_up<<<dim3(56, 16), 256, 0, stream>>>(
      (ush*)(ws + CQH), (ush*)(ws + WQH),
      (ush*)(ws + CKVH), (ush*)(ws + WKVUH),
      (ush*)(ws + QUPF), (ush*)(ws + KVF));

  // builders v2: 6272 elementwise blocks + 512 vtrans = 6784
  build_all<<<dim3(6784), 256, 0, stream>>>(
      (const ush*)(ws + QUPF), (const ush*)(ws + KVF), (const float*)(ws + KRL),
      (const float*)(ws + TAB), (ush*)(ws + QB), (ush*)(ws + KBT), (ush*)(ws + VTT));

  // attn: 256 blocks (8 qx x 16 h x z=2), 512 threads
  attn_fused<<<dim3(8, 16, 2), 512, 0, stream>>>(
      (ush*)(ws + QB), (ush*)(ws + KBT), (ush*)(ws + VTT),
      (ush*)(ws + OPART), (float*)(ws + ML));
  // reduce: 32768 rows x 32 lanes = 4096 blocks
  attn_reduce<<<dim3(4096), 256, 0, stream>>>((const ush*)(ws + OPART), (const float*)(ws + ML),
                                              (ush*)(ws + ATTNH));

  // out: (2048x2048)*(2048x2048)^T -> d_out f32
  gemm_out<<<dim3(32, 16), 256, 0, stream>>>(
      (ush*)(ws + ATTNH), (ush*)(ws + WOH), (float*)d_out, 2048, 2048);
}